// Round 2
// baseline (2506.826 us; speedup 1.0000x reference)
//
#include <hip/hip_runtime.h>

#define N_NODES 10000
#define N_EDGES 160000
#define BATCH   8
#define D       128
#define TWO_D   256
#define EPS     1e-5f
#define TE      32   // rows (edges or nodes) per block

// ---------------------------------------------------------------------------
// zero the inbox accumulator (float4 grid-stride)
// ---------------------------------------------------------------------------
__global__ void zero_kernel(float4* __restrict__ p, long long n4) {
    long long idx    = (long long)blockIdx.x * blockDim.x + threadIdx.x;
    long long stride = (long long)gridDim.x * blockDim.x;
    const float4 z = {0.f, 0.f, 0.f, 0.f};
    for (long long i = idx; i < n4; i += stride) p[i] = z;
}

// ---------------------------------------------------------------------------
// edge kernel: per block, 32 edges. Gather [recv||send] rows -> LDS,
// GEMM vs Wm (64-k tiles staged TRANSPOSED into LDS from the original
// [128][256] layout -- no workspace needed), +bias, LayerNorm per edge,
// atomicAdd into inbox[b][recv].
// Thread map: og = tid&31 -> outputs 4og..4og+3 ; eg = tid>>5 -> edges 4eg..4eg+3
// ---------------------------------------------------------------------------
__global__ __launch_bounds__(256, 2)
void edge_kernel(const float* __restrict__ nodes,
                 const float* __restrict__ Wm,   // [D][2D] row-major
                 const float* __restrict__ bm,
                 const float* __restrict__ g1,
                 const float* __restrict__ b1,
                 const int*   __restrict__ senders,
                 const int*   __restrict__ receivers,
                 float* __restrict__ inbox) {
    __shared__ __align__(16) float ldsE[TWO_D][TE + 4];  // [k][edge], pad keeps 16B align
    __shared__ __align__(16) float ldsW[64 * D];         // one 64-k tile, [k2][o]

    const int tid = threadIdx.x;
    const int b   = blockIdx.y;
    const int e0  = blockIdx.x * TE;
    const float* nb = nodes + (size_t)b * N_NODES * D;

    // ---- gather stage: 8 threads per edge, float4 per load ----
    {
        const int i  = tid >> 3;   // edge slot 0..31
        const int q0 = tid & 7;
        const int e  = e0 + i;
        const float* rowR = nb + (size_t)receivers[e] * D;
        const float* rowS = nb + (size_t)senders[e] * D;
#pragma unroll
        for (int j = 0; j < 8; ++j) {
            const int k = (j * 8 + q0) * 4;            // 0..252
            const float4 v = (k < D) ? *(const float4*)(rowR + k)
                                     : *(const float4*)(rowS + (k - D));
            ldsE[k + 0][i] = v.x;
            ldsE[k + 1][i] = v.y;
            ldsE[k + 2][i] = v.z;
            ldsE[k + 3][i] = v.w;
        }
    }

    float acc[4][4];
#pragma unroll
    for (int a = 0; a < 4; ++a)
#pragma unroll
        for (int c = 0; c < 4; ++c) acc[a][c] = 0.0f;

    const int og = tid & 31;
    const int eg = tid >> 5;

    for (int kt = 0; kt < 4; ++kt) {
        __syncthreads();
        {   // stage 64x128 weight tile TRANSPOSED: ldsW[k2*D+o] = Wm[o][kt*64+k2]
            // 2 threads per row o; float4 along k; LDS write bank = o%32 -> 2-way (free)
            const int o    = tid >> 1;
            const int half = tid & 1;
            const float* wrow = Wm + o * TWO_D + kt * 64 + half * 32;
#pragma unroll
            for (int j = 0; j < 8; ++j) {
                const float4 w4 = *(const float4*)(wrow + j * 4);
                const int k2 = half * 32 + j * 4;
                ldsW[(k2 + 0) * D + o] = w4.x;
                ldsW[(k2 + 1) * D + o] = w4.y;
                ldsW[(k2 + 2) * D + o] = w4.z;
                ldsW[(k2 + 3) * D + o] = w4.w;
            }
        }
        __syncthreads();
#pragma unroll 4
        for (int k2 = 0; k2 < 64; ++k2) {
            const float4 w = *(const float4*)&ldsW[k2 * D + 4 * og];
            const float4 x = *(const float4*)&ldsE[kt * 64 + k2][4 * eg];
            const float wv[4] = {w.x, w.y, w.z, w.w};
            const float xv[4] = {x.x, x.y, x.z, x.w};
#pragma unroll
            for (int a = 0; a < 4; ++a)
#pragma unroll
                for (int c = 0; c < 4; ++c)
                    acc[a][c] = fmaf(xv[a], wv[c], acc[a][c]);
        }
    }

    // ---- bias + LayerNorm per edge (reduce across 32 og-lanes, wave-local) ----
    const float4 bmv = *(const float4*)&bm[4 * og];
    const float4 g1v = *(const float4*)&g1[4 * og];
    const float4 b1v = *(const float4*)&b1[4 * og];
#pragma unroll
    for (int a = 0; a < 4; ++a) {
        acc[a][0] += bmv.x; acc[a][1] += bmv.y;
        acc[a][2] += bmv.z; acc[a][3] += bmv.w;
    }

    float mu[4], rs[4];
#pragma unroll
    for (int a = 0; a < 4; ++a) {
        float s = acc[a][0] + acc[a][1] + acc[a][2] + acc[a][3];
#pragma unroll
        for (int m = 16; m >= 1; m >>= 1) s += __shfl_xor(s, m, 64);
        mu[a] = s * (1.0f / 128.0f);
        const float d0 = acc[a][0] - mu[a], d1 = acc[a][1] - mu[a];
        const float d2 = acc[a][2] - mu[a], d3 = acc[a][3] - mu[a];
        float q = d0 * d0 + d1 * d1 + d2 * d2 + d3 * d3;
#pragma unroll
        for (int m = 16; m >= 1; m >>= 1) q += __shfl_xor(q, m, 64);
        rs[a] = rsqrtf(q * (1.0f / 128.0f) + EPS);
    }

    // ---- scatter-add LN'd messages into inbox ----
#pragma unroll
    for (int a = 0; a < 4; ++a) {
        const int e = e0 + 4 * eg + a;
        const int r = receivers[e];
        float* dst = inbox + ((size_t)b * N_NODES + r) * D + 4 * og;
        const float v0 = (acc[a][0] - mu[a]) * rs[a] * g1v.x + b1v.x;
        const float v1 = (acc[a][1] - mu[a]) * rs[a] * g1v.y + b1v.y;
        const float v2 = (acc[a][2] - mu[a]) * rs[a] * g1v.z + b1v.z;
        const float v3 = (acc[a][3] - mu[a]) * rs[a] * g1v.w + b1v.w;
        atomicAdd(dst + 0, v0);
        atomicAdd(dst + 1, v1);
        atomicAdd(dst + 2, v2);
        atomicAdd(dst + 3, v3);
    }
}

// ---------------------------------------------------------------------------
// node kernel: per block, 32 nodes. node_in = [nodes || inbox] -> GEMM vs Wn
// -> +bias -> LayerNorm -> write out. Bounds-guarded (10000 % 32 != 0).
// Safe even when inbox aliases out: each block's inbox reads (gather, first)
// cover exactly the rows its out writes (epilogue, last) touch; rows are
// disjoint across blocks.
// ---------------------------------------------------------------------------
__global__ __launch_bounds__(256, 2)
void node_kernel(const float* __restrict__ nodes,
                 const float* __restrict__ inbox,
                 const float* __restrict__ Wn,   // [D][2D] row-major
                 const float* __restrict__ bn,
                 const float* __restrict__ g2,
                 const float* __restrict__ b2,
                 float* __restrict__ out) {
    __shared__ __align__(16) float ldsE[TWO_D][TE + 4];
    __shared__ __align__(16) float ldsW[64 * D];

    const int tid = threadIdx.x;
    const int b   = blockIdx.y;
    const int n0  = blockIdx.x * TE;

    {
        const int i  = tid >> 3;
        const int q0 = tid & 7;
        int n = n0 + i;
        if (n >= N_NODES) n = N_NODES - 1;   // clamp loads; stores are guarded
        const float* rowN = nodes + ((size_t)b * N_NODES + n) * D;
        const float* rowI = inbox + ((size_t)b * N_NODES + n) * D;
#pragma unroll
        for (int j = 0; j < 8; ++j) {
            const int k = (j * 8 + q0) * 4;
            const float4 v = (k < D) ? *(const float4*)(rowN + k)
                                     : *(const float4*)(rowI + (k - D));
            ldsE[k + 0][i] = v.x;
            ldsE[k + 1][i] = v.y;
            ldsE[k + 2][i] = v.z;
            ldsE[k + 3][i] = v.w;
        }
    }

    float acc[4][4];
#pragma unroll
    for (int a = 0; a < 4; ++a)
#pragma unroll
        for (int c = 0; c < 4; ++c) acc[a][c] = 0.0f;

    const int og = tid & 31;
    const int eg = tid >> 5;

    for (int kt = 0; kt < 4; ++kt) {
        __syncthreads();
        {   // stage transposed Wn tile
            const int o    = tid >> 1;
            const int half = tid & 1;
            const float* wrow = Wn + o * TWO_D + kt * 64 + half * 32;
#pragma unroll
            for (int j = 0; j < 8; ++j) {
                const float4 w4 = *(const float4*)(wrow + j * 4);
                const int k2 = half * 32 + j * 4;
                ldsW[(k2 + 0) * D + o] = w4.x;
                ldsW[(k2 + 1) * D + o] = w4.y;
                ldsW[(k2 + 2) * D + o] = w4.z;
                ldsW[(k2 + 3) * D + o] = w4.w;
            }
        }
        __syncthreads();
#pragma unroll 4
        for (int k2 = 0; k2 < 64; ++k2) {
            const float4 w = *(const float4*)&ldsW[k2 * D + 4 * og];
            const float4 x = *(const float4*)&ldsE[kt * 64 + k2][4 * eg];
            const float wv[4] = {w.x, w.y, w.z, w.w};
            const float xv[4] = {x.x, x.y, x.z, x.w};
#pragma unroll
            for (int a = 0; a < 4; ++a)
#pragma unroll
                for (int c = 0; c < 4; ++c)
                    acc[a][c] = fmaf(xv[a], wv[c], acc[a][c]);
        }
    }

    const float4 bnv = *(const float4*)&bn[4 * og];
    const float4 g2v = *(const float4*)&g2[4 * og];
    const float4 b2v = *(const float4*)&b2[4 * og];
#pragma unroll
    for (int a = 0; a < 4; ++a) {
        acc[a][0] += bnv.x; acc[a][1] += bnv.y;
        acc[a][2] += bnv.z; acc[a][3] += bnv.w;
    }

    float mu[4], rs[4];
#pragma unroll
    for (int a = 0; a < 4; ++a) {
        float s = acc[a][0] + acc[a][1] + acc[a][2] + acc[a][3];
#pragma unroll
        for (int m = 16; m >= 1; m >>= 1) s += __shfl_xor(s, m, 64);
        mu[a] = s * (1.0f / 128.0f);
        const float d0 = acc[a][0] - mu[a], d1 = acc[a][1] - mu[a];
        const float d2 = acc[a][2] - mu[a], d3 = acc[a][3] - mu[a];
        float q = d0 * d0 + d1 * d1 + d2 * d2 + d3 * d3;
#pragma unroll
        for (int m = 16; m >= 1; m >>= 1) q += __shfl_xor(q, m, 64);
        rs[a] = rsqrtf(q * (1.0f / 128.0f) + EPS);
    }

#pragma unroll
    for (int a = 0; a < 4; ++a) {
        const int n = n0 + 4 * eg + a;
        if (n < N_NODES) {
            float4 o4;
            o4.x = (acc[a][0] - mu[a]) * rs[a] * g2v.x + b2v.x;
            o4.y = (acc[a][1] - mu[a]) * rs[a] * g2v.y + b2v.y;
            o4.z = (acc[a][2] - mu[a]) * rs[a] * g2v.z + b2v.z;
            o4.w = (acc[a][3] - mu[a]) * rs[a] * g2v.w + b2v.w;
            *(float4*)(out + ((size_t)b * N_NODES + n) * D + 4 * og) = o4;
        }
    }
}

// ---------------------------------------------------------------------------
extern "C" void kernel_launch(void* const* d_in, const int* in_sizes, int n_in,
                              void* d_out, int out_size, void* d_ws, size_t ws_size,
                              hipStream_t stream) {
    const float* nodes     = (const float*)d_in[0];
    const float* Wm        = (const float*)d_in[1];
    const float* bm        = (const float*)d_in[2];
    const float* g1        = (const float*)d_in[3];
    const float* b1        = (const float*)d_in[4];
    const float* Wn        = (const float*)d_in[5];
    const float* bn        = (const float*)d_in[6];
    const float* g2        = (const float*)d_in[7];
    const float* b2        = (const float*)d_in[8];
    const int*   senders   = (const int*)d_in[9];
    const int*   receivers = (const int*)d_in[10];
    float*       out       = (float*)d_out;

    const long long inbox_n = (long long)BATCH * N_NODES * D;  // 10.24M floats
    // inbox: use workspace only if it's provably big enough; else alias d_out
    // (safe -- see node_kernel header comment). NO unconditional d_ws writes.
    float* inbox = (d_ws != nullptr &&
                    ws_size >= (size_t)inbox_n * sizeof(float))
                       ? (float*)d_ws
                       : out;

    zero_kernel<<<dim3(2048), dim3(256), 0, stream>>>((float4*)inbox, inbox_n / 4);

    edge_kernel<<<dim3(N_EDGES / TE, BATCH), dim3(256), 0, stream>>>(
        nodes, Wm, bm, g1, b1, senders, receivers, inbox);

    node_kernel<<<dim3((N_NODES + TE - 1) / TE, BATCH), dim3(256), 0, stream>>>(
        nodes, inbox, Wn, bn, g2, b2, out);
}

// Round 3
// 993.738 us; speedup vs baseline: 2.5226x; 2.5226x over previous
//
#include <hip/hip_runtime.h>

#define N_NODES 10000
#define N_EDGES 160000
#define BATCH   8
#define D       128
#define TWO_D   256
#define EPS     1e-5f
#define ETILE   32   // edges per block (MFMA path)

// ---------------- bf16 helpers (bit-level, RNE) ----------------
static __device__ __forceinline__ unsigned short f2bf(float x) {
    unsigned int u = __float_as_uint(x);
    unsigned int r = (u + 0x7fffu + ((u >> 16) & 1u)) >> 16;
    return (unsigned short)r;
}
static __device__ __forceinline__ float bf2f(unsigned short b) {
    return __uint_as_float(((unsigned int)b) << 16);
}

typedef __attribute__((ext_vector_type(8)))  short          bf16x8;
typedef __attribute__((ext_vector_type(16))) float          f32x16;
typedef __attribute__((ext_vector_type(4)))  unsigned short us4;

// ---------------- generic zero ----------------
__global__ void zero_kernel(float4* __restrict__ p, long long n4) {
    long long idx    = (long long)blockIdx.x * blockDim.x + threadIdx.x;
    long long stride = (long long)gridDim.x * blockDim.x;
    const float4 z = {0.f, 0.f, 0.f, 0.f};
    for (long long i = idx; i < n4; i += stride) p[i] = z;
}

// ---------------- W image prep: split Wm into bf16 hi/lo, pre-swizzled ----
// Image: 4 chunks (64 k each) of 32KB. Chunk layout: [o=128][16 slots x 16B].
// Slot s at row o holds id = s ^ (o&15); id<8 -> hi k-group id, else lo group id-8.
__global__ void prep_w(const float* __restrict__ Wm, unsigned char* __restrict__ wimg) {
    int t = blockIdx.x * blockDim.x + threadIdx.x;
    if (t >= 4 * 128 * 16) return;
    int s = t & 15, o = (t >> 4) & 127, c = t >> 11;
    int id = s ^ (o & 15);
    int k0 = c * 64 + (id & 7) * 8;
    bool lo = id >= 8;
    unsigned short us[8];
#pragma unroll
    for (int j = 0; j < 8; ++j) {
        float x = Wm[o * TWO_D + k0 + j];
        unsigned short h = f2bf(x);
        us[j] = lo ? f2bf(x - bf2f(h)) : h;
    }
    uint4 pack;
    pack.x = (unsigned)us[0] | ((unsigned)us[1] << 16);
    pack.y = (unsigned)us[2] | ((unsigned)us[3] << 16);
    pack.z = (unsigned)us[4] | ((unsigned)us[5] << 16);
    pack.w = (unsigned)us[6] | ((unsigned)us[7] << 16);
    *(uint4*)(wimg + (size_t)c * 32768 + o * 256 + s * 16) = pack;
}

// ---------------- counting sort of edges by receiver ----------------
__global__ void hist_kernel(const int* __restrict__ recv, int* __restrict__ counts) {
    int e = blockIdx.x * blockDim.x + threadIdx.x;
    if (e < N_EDGES) atomicAdd(&counts[recv[e]], 1);
}

__global__ __launch_bounds__(1024)
void scan_kernel(const int* __restrict__ counts, int* __restrict__ cursor) {
    __shared__ int tmp[1024];
    int t = threadIdx.x;
    int local[10];
    int s = 0;
#pragma unroll
    for (int j = 0; j < 10; ++j) {
        int idx = t * 10 + j;
        int v = (idx < N_NODES) ? counts[idx] : 0;
        local[j] = s; s += v;
    }
    tmp[t] = s; __syncthreads();
    for (int off = 1; off < 1024; off <<= 1) {
        int v = tmp[t];
        int add = (t >= off) ? tmp[t - off] : 0;
        __syncthreads();
        tmp[t] = v + add;
        __syncthreads();
    }
    int base = (t > 0) ? tmp[t - 1] : 0;
#pragma unroll
    for (int j = 0; j < 10; ++j) {
        int idx = t * 10 + j;
        if (idx < N_NODES) cursor[idx] = base + local[j];
    }
}

__global__ void scatter_kernel(const int* __restrict__ recv, int* __restrict__ cursor,
                               int* __restrict__ perm) {
    int e = blockIdx.x * blockDim.x + threadIdx.x;
    if (e < N_EDGES) {
        int p = atomicAdd(&cursor[recv[e]], 1);
        perm[p] = e;
    }
}

// ---------------- MFMA edge kernel ----------------
// Block: 32 receiver-sorted edges x 128 outs, batch = blockIdx.y.
// 4 waves, wave w owns outs 32w..32w+31 (one 32x32 C tile), K=256 via
// 4 chunks x 4 ksteps, 3 split MFMAs per kstep (XhWh + XhWl + XlWh).
// X LDS: bf16 hi/lo [32][256], slot swizzle k8 ^ row. W chunk: linear copy
// of pre-swizzled image. LN cross-wave via small LDS arrays. Scatter:
// per-column run-merge over sorted receivers -> few atomics.
__global__ __launch_bounds__(256, 2)
void edge_mfma(const float* __restrict__ nodes,
               const unsigned char* __restrict__ wimg,
               const float* __restrict__ bm,
               const float* __restrict__ g1,
               const float* __restrict__ b1,
               const int*   __restrict__ senders,
               const int*   __restrict__ receivers,
               const int*   __restrict__ perm,
               float* __restrict__ inbox) {
    __shared__ __align__(16) unsigned char lds[65536]; // [0,16K) Xh | [16K,32K) Xl | [32K,64K) Wchunk ; msg overlays [0,16K)
    __shared__ int   ldsRecv[ETILE];
    __shared__ int   ldsSend[ETILE];
    __shared__ float ldsSum[4][ETILE];
    __shared__ float ldsSq[4][ETILE];
    __shared__ float ldsMu[ETILE];
    __shared__ float ldsRs[ETILE];

    const int tid = threadIdx.x;
    const int b   = blockIdx.y;
    const int e0  = blockIdx.x * ETILE;
    const int w      = tid >> 6;
    const int l      = tid & 63;
    const int lane31 = l & 31;
    const int hiG    = l >> 5;

    if (tid < ETILE) {
        int pe = perm[e0 + tid];
        ldsRecv[tid] = receivers[pe];
        ldsSend[tid] = senders[pe];
    }
    __syncthreads();

    // ---- gather + bf16 hi/lo split into swizzled LDS ----
    {
        const int i = tid >> 3;   // edge slot
        const int q = tid & 7;
        const float* nb   = nodes + (size_t)b * N_NODES * D;
        const float* rowR = nb + (size_t)ldsRecv[i] * D;
        const float* rowS = nb + (size_t)ldsSend[i] * D;
        unsigned char* xh = lds;
        unsigned char* xl = lds + 16384;
#pragma unroll
        for (int j = 0; j < 8; ++j) {
            int kq = j * 8 + q;            // float4 index 0..63
            int kf = kq * 4;
            float4 v = (kf < D) ? *(const float4*)(rowR + kf)
                                : *(const float4*)(rowS + (kf - D));
            unsigned short h0 = f2bf(v.x), h1 = f2bf(v.y), h2 = f2bf(v.z), h3 = f2bf(v.w);
            us4 hv = {h0, h1, h2, h3};
            us4 lv = {f2bf(v.x - bf2f(h0)), f2bf(v.y - bf2f(h1)),
                      f2bf(v.z - bf2f(h2)), f2bf(v.w - bf2f(h3))};
            int k8 = kq >> 1, sub = kq & 1;
            int off = i * 512 + ((k8 ^ i) << 4) + sub * 8;
            *(us4*)(xh + off) = hv;
            *(us4*)(xl + off) = lv;
        }
    }

    f32x16 acc;
#pragma unroll
    for (int i = 0; i < 16; ++i) acc[i] = 0.f;

    const int o = w * 32 + lane31;   // this lane's output column
    for (int c = 0; c < 4; ++c) {
        {   // stage W chunk c: 32KB linear copy (image already split+swizzled)
            const uint4* src = (const uint4*)(wimg + (size_t)c * 32768);
            uint4*       dst = (uint4*)(lds + 32768);
#pragma unroll
            for (int it = 0; it < 8; ++it) dst[it * 256 + tid] = src[it * 256 + tid];
        }
        __syncthreads();   // (iter 0 also publishes X)
        const unsigned char* xh = lds;
        const unsigned char* xl = lds + 16384;
        const unsigned char* wc = lds + 32768;
#pragma unroll
        for (int kl = 0; kl < 4; ++kl) {
            int k8 = c * 8 + kl * 2 + hiG;
            const bf16x8 ah = *(const bf16x8*)(xh + lane31 * 512 + ((k8 ^ lane31) << 4));
            const bf16x8 al = *(const bf16x8*)(xl + lane31 * 512 + ((k8 ^ lane31) << 4));
            int id = kl * 2 + hiG;
            const bf16x8 bh = *(const bf16x8*)(wc + o * 256 + ((id ^ (o & 15)) << 4));
            const bf16x8 bl = *(const bf16x8*)(wc + o * 256 + (((id | 8) ^ (o & 15)) << 4));
            acc = __builtin_amdgcn_mfma_f32_32x32x16_bf16(ah, bh, acc, 0, 0, 0);
            acc = __builtin_amdgcn_mfma_f32_32x32x16_bf16(ah, bl, acc, 0, 0, 0);
            acc = __builtin_amdgcn_mfma_f32_32x32x16_bf16(al, bh, acc, 0, 0, 0);
        }
        __syncthreads();   // chunk consumed; safe to overwrite (and, last iter, overlay msg)
    }

    // ---- bias + LayerNorm stats (reduce over 128 outs per edge) ----
    const float bmv = bm[o], g1v = g1[o], b1v = b1[o];
    float v[16], sr[16], qr[16];
#pragma unroll
    for (int r = 0; r < 16; ++r) {
        v[r] = acc[r] + bmv;
        sr[r] = v[r];
        qr[r] = v[r] * v[r];
    }
#pragma unroll
    for (int m = 16; m >= 1; m >>= 1) {
#pragma unroll
        for (int r = 0; r < 16; ++r) {
            sr[r] += __shfl_xor(sr[r], m, 64);
            qr[r] += __shfl_xor(qr[r], m, 64);
        }
    }
    if (lane31 == 0) {
#pragma unroll
        for (int r = 0; r < 16; ++r) {
            int m = (r & 3) + 8 * (r >> 2) + 4 * hiG;
            ldsSum[w][m] = sr[r];
            ldsSq[w][m]  = qr[r];
        }
    }
    __syncthreads();
    if (tid < ETILE) {
        float S = ldsSum[0][tid] + ldsSum[1][tid] + ldsSum[2][tid] + ldsSum[3][tid];
        float Q = ldsSq[0][tid]  + ldsSq[1][tid]  + ldsSq[2][tid]  + ldsSq[3][tid];
        float mu  = S * (1.f / 128.f);
        float var = Q * (1.f / 128.f) - mu * mu;
        ldsMu[tid] = mu;
        ldsRs[tid] = rsqrtf(var + EPS);
    }
    __syncthreads();

    // ---- normalized messages -> LDS [32][128] fp32 (overlays X) ----
    float* msg = (float*)lds;
#pragma unroll
    for (int r = 0; r < 16; ++r) {
        int m = (r & 3) + 8 * (r >> 2) + 4 * hiG;
        msg[m * 128 + o] = (v[r] - ldsMu[m]) * ldsRs[m] * g1v + b1v;
    }
    __syncthreads();

    // ---- scatter: per-column run-merge over sorted receivers ----
    {
        int col  = tid & 127;
        int half = tid >> 7;
        float* base = inbox + (size_t)b * N_NODES * D + col;
        int prev = -1; float accu = 0.f;
#pragma unroll
        for (int i = 0; i < 16; ++i) {
            int e = half * 16 + i;
            int r = ldsRecv[e];
            float val = msg[e * 128 + col];
            if (r != prev) {
                if (prev >= 0) atomicAdd(base + (size_t)prev * D, accu);
                prev = r; accu = val;
            } else {
                accu += val;
            }
        }
        if (prev >= 0) atomicAdd(base + (size_t)prev * D, accu);
    }
}

// ---------------- fp32 fallback edge kernel (R2, proven) ----------------
__global__ __launch_bounds__(256, 2)
void edge_kernel(const float* __restrict__ nodes,
                 const float* __restrict__ Wm,
                 const float* __restrict__ bm,
                 const float* __restrict__ g1,
                 const float* __restrict__ b1,
                 const int*   __restrict__ senders,
                 const int*   __restrict__ receivers,
                 float* __restrict__ inbox) {
    __shared__ __align__(16) float ldsE[TWO_D][36];
    __shared__ __align__(16) float ldsW[64 * D];
    const int tid = threadIdx.x;
    const int b   = blockIdx.y;
    const int e0  = blockIdx.x * 32;
    const float* nb = nodes + (size_t)b * N_NODES * D;
    {
        const int i = tid >> 3, q0 = tid & 7, e = e0 + i;
        const float* rowR = nb + (size_t)receivers[e] * D;
        const float* rowS = nb + (size_t)senders[e] * D;
#pragma unroll
        for (int j = 0; j < 8; ++j) {
            const int k = (j * 8 + q0) * 4;
            const float4 v = (k < D) ? *(const float4*)(rowR + k)
                                     : *(const float4*)(rowS + (k - D));
            ldsE[k + 0][i] = v.x; ldsE[k + 1][i] = v.y;
            ldsE[k + 2][i] = v.z; ldsE[k + 3][i] = v.w;
        }
    }
    float acc[4][4];
#pragma unroll
    for (int a = 0; a < 4; ++a)
#pragma unroll
        for (int c = 0; c < 4; ++c) acc[a][c] = 0.0f;
    const int og = tid & 31, eg = tid >> 5;
    for (int kt = 0; kt < 4; ++kt) {
        __syncthreads();
        {
            const int oo = tid >> 1, half = tid & 1;
            const float* wrow = Wm + oo * TWO_D + kt * 64 + half * 32;
#pragma unroll
            for (int j = 0; j < 8; ++j) {
                const float4 w4 = *(const float4*)(wrow + j * 4);
                const int k2 = half * 32 + j * 4;
                ldsW[(k2 + 0) * D + oo] = w4.x; ldsW[(k2 + 1) * D + oo] = w4.y;
                ldsW[(k2 + 2) * D + oo] = w4.z; ldsW[(k2 + 3) * D + oo] = w4.w;
            }
        }
        __syncthreads();
#pragma unroll 4
        for (int k2 = 0; k2 < 64; ++k2) {
            const float4 wv = *(const float4*)&ldsW[k2 * D + 4 * og];
            const float4 xv = *(const float4*)&ldsE[kt * 64 + k2][4 * eg];
            const float wa[4] = {wv.x, wv.y, wv.z, wv.w};
            const float xa[4] = {xv.x, xv.y, xv.z, xv.w};
#pragma unroll
            for (int a = 0; a < 4; ++a)
#pragma unroll
                for (int c = 0; c < 4; ++c)
                    acc[a][c] = fmaf(xa[a], wa[c], acc[a][c]);
        }
    }
    const float4 bmv = *(const float4*)&bm[4 * og];
    const float4 g1v = *(const float4*)&g1[4 * og];
    const float4 b1v = *(const float4*)&b1[4 * og];
#pragma unroll
    for (int a = 0; a < 4; ++a) {
        acc[a][0] += bmv.x; acc[a][1] += bmv.y;
        acc[a][2] += bmv.z; acc[a][3] += bmv.w;
    }
    float mu[4], rs[4];
#pragma unroll
    for (int a = 0; a < 4; ++a) {
        float s = acc[a][0] + acc[a][1] + acc[a][2] + acc[a][3];
#pragma unroll
        for (int m = 16; m >= 1; m >>= 1) s += __shfl_xor(s, m, 64);
        mu[a] = s * (1.0f / 128.0f);
        const float d0 = acc[a][0] - mu[a], d1 = acc[a][1] - mu[a];
        const float d2 = acc[a][2] - mu[a], d3 = acc[a][3] - mu[a];
        float q = d0 * d0 + d1 * d1 + d2 * d2 + d3 * d3;
#pragma unroll
        for (int m = 16; m >= 1; m >>= 1) q += __shfl_xor(q, m, 64);
        rs[a] = rsqrtf(q * (1.0f / 128.0f) + EPS);
    }
#pragma unroll
    for (int a = 0; a < 4; ++a) {
        const int e = e0 + 4 * eg + a;
        const int r = receivers[e];
        float* dst = inbox + ((size_t)b * N_NODES + r) * D + 4 * og;
        atomicAdd(dst + 0, (acc[a][0] - mu[a]) * rs[a] * g1v.x + b1v.x);
        atomicAdd(dst + 1, (acc[a][1] - mu[a]) * rs[a] * g1v.y + b1v.y);
        atomicAdd(dst + 2, (acc[a][2] - mu[a]) * rs[a] * g1v.z + b1v.z);
        atomicAdd(dst + 3, (acc[a][3] - mu[a]) * rs[a] * g1v.w + b1v.w);
    }
}

// ---------------- node kernel (fp32, proven) ----------------
__global__ __launch_bounds__(256, 2)
void node_kernel(const float* __restrict__ nodes,
                 const float* __restrict__ inbox,
                 const float* __restrict__ Wn,
                 const float* __restrict__ bn,
                 const float* __restrict__ g2,
                 const float* __restrict__ b2,
                 float* __restrict__ out) {
    __shared__ __align__(16) float ldsE[TWO_D][36];
    __shared__ __align__(16) float ldsW[64 * D];
    const int tid = threadIdx.x;
    const int b   = blockIdx.y;
    const int n0  = blockIdx.x * 32;
    {
        const int i = tid >> 3, q0 = tid & 7;
        int n = n0 + i;
        if (n >= N_NODES) n = N_NODES - 1;
        const float* rowN = nodes + ((size_t)b * N_NODES + n) * D;
        const float* rowI = inbox + ((size_t)b * N_NODES + n) * D;
#pragma unroll
        for (int j = 0; j < 8; ++j) {
            const int k = (j * 8 + q0) * 4;
            const float4 v = (k < D) ? *(const float4*)(rowN + k)
                                     : *(const float4*)(rowI + (k - D));
            ldsE[k + 0][i] = v.x; ldsE[k + 1][i] = v.y;
            ldsE[k + 2][i] = v.z; ldsE[k + 3][i] = v.w;
        }
    }
    float acc[4][4];
#pragma unroll
    for (int a = 0; a < 4; ++a)
#pragma unroll
        for (int c = 0; c < 4; ++c) acc[a][c] = 0.0f;
    const int og = tid & 31, eg = tid >> 5;
    for (int kt = 0; kt < 4; ++kt) {
        __syncthreads();
        {
            const int oo = tid >> 1, half = tid & 1;
            const float* wrow = Wn + oo * TWO_D + kt * 64 + half * 32;
#pragma unroll
            for (int j = 0; j < 8; ++j) {
                const float4 w4 = *(const float4*)(wrow + j * 4);
                const int k2 = half * 32 + j * 4;
                ldsW[(k2 + 0) * D + oo] = w4.x; ldsW[(k2 + 1) * D + oo] = w4.y;
                ldsW[(k2 + 2) * D + oo] = w4.z; ldsW[(k2 + 3) * D + oo] = w4.w;
            }
        }
        __syncthreads();
#pragma unroll 4
        for (int k2 = 0; k2 < 64; ++k2) {
            const float4 wv = *(const float4*)&ldsW[k2 * D + 4 * og];
            const float4 xv = *(const float4*)&ldsE[kt * 64 + k2][4 * eg];
            const float wa[4] = {wv.x, wv.y, wv.z, wv.w};
            const float xa[4] = {xv.x, xv.y, xv.z, xv.w};
#pragma unroll
            for (int a = 0; a < 4; ++a)
#pragma unroll
                for (int c = 0; c < 4; ++c)
                    acc[a][c] = fmaf(xa[a], wa[c], acc[a][c]);
        }
    }
    const float4 bnv = *(const float4*)&bn[4 * og];
    const float4 g2v = *(const float4*)&g2[4 * og];
    const float4 b2v = *(const float4*)&b2[4 * og];
#pragma unroll
    for (int a = 0; a < 4; ++a) {
        acc[a][0] += bnv.x; acc[a][1] += bnv.y;
        acc[a][2] += bnv.z; acc[a][3] += bnv.w;
    }
    float mu[4], rs[4];
#pragma unroll
    for (int a = 0; a < 4; ++a) {
        float s = acc[a][0] + acc[a][1] + acc[a][2] + acc[a][3];
#pragma unroll
        for (int m = 16; m >= 1; m >>= 1) s += __shfl_xor(s, m, 64);
        mu[a] = s * (1.0f / 128.0f);
        const float d0 = acc[a][0] - mu[a], d1 = acc[a][1] - mu[a];
        const float d2 = acc[a][2] - mu[a], d3 = acc[a][3] - mu[a];
        float q = d0 * d0 + d1 * d1 + d2 * d2 + d3 * d3;
#pragma unroll
        for (int m = 16; m >= 1; m >>= 1) q += __shfl_xor(q, m, 64);
        rs[a] = rsqrtf(q * (1.0f / 128.0f) + EPS);
    }
#pragma unroll
    for (int a = 0; a < 4; ++a) {
        const int n = n0 + 4 * eg + a;
        if (n < N_NODES) {
            float4 o4;
            o4.x = (acc[a][0] - mu[a]) * rs[a] * g2v.x + b2v.x;
            o4.y = (acc[a][1] - mu[a]) * rs[a] * g2v.y + b2v.y;
            o4.z = (acc[a][2] - mu[a]) * rs[a] * g2v.z + b2v.z;
            o4.w = (acc[a][3] - mu[a]) * rs[a] * g2v.w + b2v.w;
            *(float4*)(out + ((size_t)b * N_NODES + n) * D + 4 * og) = o4;
        }
    }
}

// ---------------------------------------------------------------------------
extern "C" void kernel_launch(void* const* d_in, const int* in_sizes, int n_in,
                              void* d_out, int out_size, void* d_ws, size_t ws_size,
                              hipStream_t stream) {
    const float* nodes     = (const float*)d_in[0];
    const float* Wm        = (const float*)d_in[1];
    const float* bm        = (const float*)d_in[2];
    const float* g1        = (const float*)d_in[3];
    const float* b1        = (const float*)d_in[4];
    const float* Wn        = (const float*)d_in[5];
    const float* bn        = (const float*)d_in[6];
    const float* g2        = (const float*)d_in[7];
    const float* b2        = (const float*)d_in[8];
    const int*   senders   = (const int*)d_in[9];
    const int*   receivers = (const int*)d_in[10];
    float*       out       = (float*)d_out;

    const long long inbox_n = (long long)BATCH * N_NODES * D;   // 10.24M floats
    // ws layout: [0,128K) W image | [128K, 128K+~720K) sort ints | [1M, 1M+41MB) inbox
    const size_t SCRATCH_NEED = 131072 + 720128;

    if (d_ws != nullptr && ws_size >= SCRATCH_NEED) {
        unsigned char* wsb  = (unsigned char*)d_ws;
        unsigned char* wimg = wsb;
        int* ints   = (int*)(wsb + 131072);
        int* counts = ints;            // 10000 (16B aligned)
        int* cursor = ints + 10016;    // 10000
        int* perm   = ints + 20032;    // 160000
        float* inbox = (ws_size >= (size_t)1048576 + (size_t)inbox_n * 4)
                           ? (float*)(wsb + 1048576) : out;

        zero_kernel<<<dim3(10),   dim3(256), 0, stream>>>((float4*)counts, 2500);
        zero_kernel<<<dim3(2048), dim3(256), 0, stream>>>((float4*)inbox, inbox_n / 4);
        prep_w<<<dim3(32), dim3(256), 0, stream>>>(Wm, wimg);
        hist_kernel<<<dim3(625), dim3(256), 0, stream>>>(receivers, counts);
        scan_kernel<<<dim3(1), dim3(1024), 0, stream>>>(counts, cursor);
        scatter_kernel<<<dim3(625), dim3(256), 0, stream>>>(receivers, cursor, perm);

        edge_mfma<<<dim3(N_EDGES / ETILE, BATCH), dim3(256), 0, stream>>>(
            nodes, wimg, bm, g1, b1, senders, receivers, perm, inbox);

        node_kernel<<<dim3((N_NODES + 31) / 32, BATCH), dim3(256), 0, stream>>>(
            nodes, inbox, Wn, bn, g2, b2, out);
    } else {
        // proven R2 fallback (no workspace needed)
        float* inbox = out;
        zero_kernel<<<dim3(2048), dim3(256), 0, stream>>>((float4*)inbox, inbox_n / 4);
        edge_kernel<<<dim3(N_EDGES / 32, BATCH), dim3(256), 0, stream>>>(
            nodes, Wm, bm, g1, b1, senders, receivers, inbox);
        node_kernel<<<dim3((N_NODES + 31) / 32, BATCH), dim3(256), 0, stream>>>(
            nodes, inbox, Wn, bn, g2, b2, out);
    }
}

// Round 5
// 531.695 us; speedup vs baseline: 4.7148x; 1.8690x over previous
//
#include <hip/hip_runtime.h>

#define N_NODES 10000
#define N_EDGES 160000
#define BATCH   8
#define D       128
#define TWO_D   256
#define EPS     1e-5f
#define ETILE   32

typedef _Float16 f16x8  __attribute__((ext_vector_type(8)));
typedef float    f32x16 __attribute__((ext_vector_type(16)));

// ---------------- generic zero ----------------
__global__ void zero_kernel(float4* __restrict__ p, long long n4) {
    long long idx    = (long long)blockIdx.x * blockDim.x + threadIdx.x;
    long long stride = (long long)gridDim.x * blockDim.x;
    const float4 z = {0.f, 0.f, 0.f, 0.f};
    for (long long i = idx; i < n4; i += stride) p[i] = z;
}

// ---------------- W prep: f16 images in B-fragment order ----------------
// img_m[g*128 + o] (16B = 8 f16) = Wm[o][8g .. 8g+7],  g in [0,32)  (64 KB)
// img_n at +65536 likewise for Wn.
__global__ void prep_w(const float* __restrict__ Wm, const float* __restrict__ Wn,
                       unsigned char* __restrict__ img) {
    int t = blockIdx.x * blockDim.x + threadIdx.x;
    if (t >= 4096) return;
    int g = t >> 7, o = t & 127;
    f16x8 vm, vn;
#pragma unroll
    for (int j = 0; j < 8; ++j) {
        vm[j] = (_Float16)Wm[o * TWO_D + 8 * g + j];
        vn[j] = (_Float16)Wn[o * TWO_D + 8 * g + j];
    }
    ((f16x8*)img)[t]           = vm;
    ((f16x8*)(img + 65536))[t] = vn;
}

// ---------------- counting sort of edges by receiver (proven R3) ----------
__global__ void hist_kernel(const int* __restrict__ recv, int* __restrict__ counts) {
    int e = blockIdx.x * blockDim.x + threadIdx.x;
    if (e < N_EDGES) atomicAdd(&counts[recv[e]], 1);
}

__global__ __launch_bounds__(1024)
void scan_kernel(const int* __restrict__ counts, int* __restrict__ cursor) {
    __shared__ int tmp[1024];
    int t = threadIdx.x;
    int local[10];
    int s = 0;
#pragma unroll
    for (int j = 0; j < 10; ++j) {
        int idx = t * 10 + j;
        int v = (idx < N_NODES) ? counts[idx] : 0;
        local[j] = s; s += v;
    }
    tmp[t] = s; __syncthreads();
    for (int off = 1; off < 1024; off <<= 1) {
        int v = tmp[t];
        int add = (t >= off) ? tmp[t - off] : 0;
        __syncthreads();
        tmp[t] = v + add;
        __syncthreads();
    }
    int base = (t > 0) ? tmp[t - 1] : 0;
#pragma unroll
    for (int j = 0; j < 10; ++j) {
        int idx = t * 10 + j;
        if (idx < N_NODES) cursor[idx] = base + local[j];
    }
}

__global__ void scatter_kernel(const int* __restrict__ recv, int* __restrict__ cursor,
                               int* __restrict__ perm) {
    int e = blockIdx.x * blockDim.x + threadIdx.x;
    if (e < N_EDGES) {
        int p = atomicAdd(&cursor[recv[e]], 1);
        perm[p] = e;
    }
}

// ---------------- MFMA edge kernel v2 ----------------
// 128 threads = 2 waves, 32 receiver-sorted edges, 128 outs.
// Wave w holds W f16 frags for col-tiles {2w, 2w+1} in REGISTERS (loaded once).
// X: f16 hi/lo split, LDS layout [kgroup g][row] -> conflict-free b128 reads.
// k-loop: 16 ksteps x (2 ds_read_b128 + 4 MFMA), no mid-loop barriers.
// LN stats via msg-LDS transpose; LN applied inline in the sorted run-merge
// scatter (few atomics).
__global__ __launch_bounds__(128, 2)
void edge_mfma(const float* __restrict__ nodes,
               const unsigned char* __restrict__ wimg,
               const float* __restrict__ bm,
               const float* __restrict__ g1,
               const float* __restrict__ b1,
               const int*   __restrict__ senders,
               const int*   __restrict__ receivers,
               const int*   __restrict__ perm,
               float* __restrict__ inbox) {
    __shared__ __align__(16) unsigned char s_lds[33792]; // Xh[16K) Xl[16K..32K); msg fp32[32][132] overlays
    __shared__ int   s_recv[ETILE];
    __shared__ float s_mu[ETILE];
    __shared__ float s_rs[ETILE];

    const int tid = threadIdx.x;
    const int b   = blockIdx.y;
    const int e0  = blockIdx.x * ETILE;
    const int w      = tid >> 6;
    const int l      = tid & 63;
    const int lane31 = l & 31;
    const int hiG    = l >> 5;

    if (tid < ETILE) s_recv[tid] = receivers[perm[e0 + tid]];

    // ---- W fragments -> registers (once per block, coalesced from L2) ----
    f16x8 wf0[16], wf1[16];
    {
        const f16x8* img = (const f16x8*)wimg;
        const int o0 = (2 * w + 0) * 32 + lane31;
        const int o1 = (2 * w + 1) * 32 + lane31;
#pragma unroll
        for (int ks = 0; ks < 16; ++ks) {
            wf0[ks] = img[(2 * ks + hiG) * 128 + o0];
            wf1[ks] = img[(2 * ks + hiG) * 128 + o1];
        }
    }

    // ---- gather + f16 hi/lo split into [g][row] LDS ----
    {
        f16x8* Xh = (f16x8*)s_lds;
        f16x8* Xl = (f16x8*)(s_lds + 16384);
        const int i = tid >> 2;      // edge slot 0..31
        const int q = tid & 3;       // fp32 k-quarter [64q, 64q+64)
        const int pe = perm[e0 + i];
        const float* nb = nodes + (size_t)b * N_NODES * D;
        const float* row = (q < 2)
            ? (nb + (size_t)receivers[pe] * D + 64 * q)
            : (nb + (size_t)senders[pe]   * D + 64 * q - 128);
#pragma unroll
        for (int j = 0; j < 8; ++j) {
            const float4 va = *(const float4*)(row + 8 * j);
            const float4 vb = *(const float4*)(row + 8 * j + 4);
            const float xs[8] = {va.x, va.y, va.z, va.w, vb.x, vb.y, vb.z, vb.w};
            f16x8 h, lo;
#pragma unroll
            for (int u = 0; u < 8; ++u) {
                h[u]  = (_Float16)xs[u];
                lo[u] = (_Float16)(xs[u] - (float)h[u]);
            }
            const int g = 8 * q + j;
            Xh[g * 32 + i] = h;
            Xl[g * 32 + i] = lo;
        }
    }
    __syncthreads();

    // ---- k-loop: pure LDS-read + MFMA ----
    f32x16 acc0, acc1;
#pragma unroll
    for (int r = 0; r < 16; ++r) { acc0[r] = 0.f; acc1[r] = 0.f; }
    {
        const f16x8* Xh = (const f16x8*)s_lds;
        const f16x8* Xl = (const f16x8*)(s_lds + 16384);
#pragma unroll
        for (int ks = 0; ks < 16; ++ks) {
            const f16x8 ah = Xh[(2 * ks + hiG) * 32 + lane31];
            const f16x8 al = Xl[(2 * ks + hiG) * 32 + lane31];
            acc0 = __builtin_amdgcn_mfma_f32_32x32x16_f16(ah, wf0[ks], acc0, 0, 0, 0);
            acc0 = __builtin_amdgcn_mfma_f32_32x32x16_f16(al, wf0[ks], acc0, 0, 0, 0);
            acc1 = __builtin_amdgcn_mfma_f32_32x32x16_f16(ah, wf1[ks], acc1, 0, 0, 0);
            acc1 = __builtin_amdgcn_mfma_f32_32x32x16_f16(al, wf1[ks], acc1, 0, 0, 0);
        }
    }
    __syncthreads();   // all X reads done; msg overlays X region

    // ---- bias + raw messages -> msg[32][132] fp32 ----
    float* msg = (float*)s_lds;
    {
        const int o0 = (2 * w + 0) * 32 + lane31;
        const int o1 = (2 * w + 1) * 32 + lane31;
        const float bm0 = bm[o0], bm1 = bm[o1];
#pragma unroll
        for (int r = 0; r < 16; ++r) {
            const int m = (r & 3) + 8 * (r >> 2) + 4 * hiG;
            msg[m * 132 + o0] = acc0[r] + bm0;
            msg[m * 132 + o1] = acc1[r] + bm1;
        }
    }
    __syncthreads();

    // ---- LN stats (two-pass, matches reference) ----
    {
        const int m = tid >> 2, c0 = tid & 3;
        float s = 0.f;
#pragma unroll
        for (int i2 = 0; i2 < 32; ++i2) s += msg[m * 132 + c0 + 4 * i2];
        s += __shfl_xor(s, 1, 64); s += __shfl_xor(s, 2, 64);
        const float mu = s * (1.f / 128.f);
        float qq = 0.f;
#pragma unroll
        for (int i2 = 0; i2 < 32; ++i2) {
            const float dd = msg[m * 132 + c0 + 4 * i2] - mu;
            qq += dd * dd;
        }
        qq += __shfl_xor(qq, 1, 64); qq += __shfl_xor(qq, 2, 64);
        if (c0 == 0) { s_mu[m] = mu; s_rs[m] = rsqrtf(qq * (1.f / 128.f) + EPS); }
    }
    __syncthreads();

    // ---- scatter: inline LN + run-merge over sorted receivers ----
    {
        const int col = tid;
        const float gv = g1[col], bv = b1[col];
        float* base = inbox + (size_t)b * N_NODES * D + col;
        int prev = -1; float accu = 0.f;
#pragma unroll
        for (int e = 0; e < ETILE; ++e) {
            const int r = s_recv[e];
            const float val = (msg[e * 132 + col] - s_mu[e]) * s_rs[e] * gv + bv;
            if (r != prev) {
                if (prev >= 0) atomicAdd(base + (size_t)prev * D, accu);
                prev = r; accu = val;
            } else {
                accu += val;
            }
        }
        if (prev >= 0) atomicAdd(base + (size_t)prev * D, accu);
    }
}

// ---------------- MFMA node kernel v2 (same template, no scatter) --------
__global__ __launch_bounds__(128, 2)
void node_mfma(const float* __restrict__ nodes,
               const float* __restrict__ inbox,
               const unsigned char* __restrict__ wimg,
               const float* __restrict__ bn,
               const float* __restrict__ g2,
               const float* __restrict__ b2,
               float* __restrict__ out) {
    __shared__ __align__(16) unsigned char s_lds[33792];
    __shared__ float s_mu[ETILE];
    __shared__ float s_rs[ETILE];

    const int tid = threadIdx.x;
    const int b   = blockIdx.y;
    const int n0  = blockIdx.x * ETILE;
    const int w      = tid >> 6;
    const int l      = tid & 63;
    const int lane31 = l & 31;
    const int hiG    = l >> 5;

    f16x8 wf0[16], wf1[16];
    {
        const f16x8* img = (const f16x8*)wimg;
        const int o0 = (2 * w + 0) * 32 + lane31;
        const int o1 = (2 * w + 1) * 32 + lane31;
#pragma unroll
        for (int ks = 0; ks < 16; ++ks) {
            wf0[ks] = img[(2 * ks + hiG) * 128 + o0];
            wf1[ks] = img[(2 * ks + hiG) * 128 + o1];
        }
    }

    {
        f16x8* Xh = (f16x8*)s_lds;
        f16x8* Xl = (f16x8*)(s_lds + 16384);
        const int i = tid >> 2;
        const int q = tid & 3;
        int n = n0 + i;
        if (n >= N_NODES) n = N_NODES - 1;   // clamp loads; stores guarded
        const float* row = (q < 2)
            ? (nodes + ((size_t)b * N_NODES + n) * D + 64 * q)
            : (inbox + ((size_t)b * N_NODES + n) * D + 64 * q - 128);
#pragma unroll
        for (int j = 0; j < 8; ++j) {
            const float4 va = *(const float4*)(row + 8 * j);
            const float4 vb = *(const float4*)(row + 8 * j + 4);
            const float xs[8] = {va.x, va.y, va.z, va.w, vb.x, vb.y, vb.z, vb.w};
            f16x8 h, lo;
#pragma unroll
            for (int u = 0; u < 8; ++u) {
                h[u]  = (_Float16)xs[u];
                lo[u] = (_Float16)(xs[u] - (float)h[u]);
            }
            const int g = 8 * q + j;
            Xh[g * 32 + i] = h;
            Xl[g * 32 + i] = lo;
        }
    }
    __syncthreads();

    f32x16 acc0, acc1;
#pragma unroll
    for (int r = 0; r < 16; ++r) { acc0[r] = 0.f; acc1[r] = 0.f; }
    {
        const f16x8* Xh = (const f16x8*)s_lds;
        const f16x8* Xl = (const f16x8*)(s_lds + 16384);
#pragma unroll
        for (int ks = 0; ks < 16; ++ks) {
            const f16x8 ah = Xh[(2 * ks + hiG) * 32 + lane31];
            const f16x8 al = Xl[(2 * ks + hiG) * 32 + lane31];
            acc0 = __builtin_amdgcn_mfma_f32_32x32x16_f16(ah, wf0[ks], acc0, 0, 0, 0);
            acc0 = __builtin_amdgcn_mfma_f32_32x32x16_f16(al, wf0[ks], acc0, 0, 0, 0);
            acc1 = __builtin_amdgcn_mfma_f32_32x32x16_f16(ah, wf1[ks], acc1, 0, 0, 0);
            acc1 = __builtin_amdgcn_mfma_f32_32x32x16_f16(al, wf1[ks], acc1, 0, 0, 0);
        }
    }
    __syncthreads();

    float* msg = (float*)s_lds;
    {
        const int o0 = (2 * w + 0) * 32 + lane31;
        const int o1 = (2 * w + 1) * 32 + lane31;
        const float bn0 = bn[o0], bn1 = bn[o1];
#pragma unroll
        for (int r = 0; r < 16; ++r) {
            const int m = (r & 3) + 8 * (r >> 2) + 4 * hiG;
            msg[m * 132 + o0] = acc0[r] + bn0;
            msg[m * 132 + o1] = acc1[r] + bn1;
        }
    }
    __syncthreads();

    {
        const int m = tid >> 2, c0 = tid & 3;
        float s = 0.f;
#pragma unroll
        for (int i2 = 0; i2 < 32; ++i2) s += msg[m * 132 + c0 + 4 * i2];
        s += __shfl_xor(s, 1, 64); s += __shfl_xor(s, 2, 64);
        const float mu = s * (1.f / 128.f);
        float qq = 0.f;
#pragma unroll
        for (int i2 = 0; i2 < 32; ++i2) {
            const float dd = msg[m * 132 + c0 + 4 * i2] - mu;
            qq += dd * dd;
        }
        qq += __shfl_xor(qq, 1, 64); qq += __shfl_xor(qq, 2, 64);
        if (c0 == 0) { s_mu[m] = mu; s_rs[m] = rsqrtf(qq * (1.f / 128.f) + EPS); }
    }
    __syncthreads();

    {
        const int col = tid;
        const float gv = g2[col], bv = b2[col];
#pragma unroll
        for (int e = 0; e < ETILE; ++e) {
            const int n = n0 + e;
            if (n < N_NODES) {
                out[((size_t)b * N_NODES + n) * D + col] =
                    (msg[e * 132 + col] - s_mu[e]) * s_rs[e] * gv + bv;
            }
        }
    }
}

// ---------------- fp32 fallback kernels (proven R2, no workspace) ---------
__global__ __launch_bounds__(256, 2)
void edge_kernel(const float* __restrict__ nodes,
                 const float* __restrict__ Wm,
                 const float* __restrict__ bm,
                 const float* __restrict__ g1,
                 const float* __restrict__ b1,
                 const int*   __restrict__ senders,
                 const int*   __restrict__ receivers,
                 float* __restrict__ inbox) {
    __shared__ __align__(16) float ldsE[TWO_D][36];
    __shared__ __align__(16) float ldsW[64 * D];
    const int tid = threadIdx.x;
    const int b   = blockIdx.y;
    const int e0  = blockIdx.x * 32;
    const float* nb = nodes + (size_t)b * N_NODES * D;
    {
        const int i = tid >> 3, q0 = tid & 7, e = e0 + i;
        const float* rowR = nb + (size_t)receivers[e] * D;
        const float* rowS = nb + (size_t)senders[e] * D;
#pragma unroll
        for (int j = 0; j < 8; ++j) {
            const int k = (j * 8 + q0) * 4;
            const float4 v = (k < D) ? *(const float4*)(rowR + k)
                                     : *(const float4*)(rowS + (k - D));
            ldsE[k + 0][i] = v.x; ldsE[k + 1][i] = v.y;
            ldsE[k + 2][i] = v.z; ldsE[k + 3][i] = v.w;
        }
    }
    float acc[4][4];
#pragma unroll
    for (int a = 0; a < 4; ++a)
#pragma unroll
        for (int c = 0; c < 4; ++c) acc[a][c] = 0.0f;
    const int og = tid & 31, eg = tid >> 5;
    for (int kt = 0; kt < 4; ++kt) {
        __syncthreads();
        {
            const int oo = tid >> 1, half = tid & 1;
            const float* wrow = Wm + oo * TWO_D + kt * 64 + half * 32;
#pragma unroll
            for (int j = 0; j < 8; ++j) {
                const float4 w4 = *(const float4*)(wrow + j * 4);
                const int k2 = half * 32 + j * 4;
                ldsW[(k2 + 0) * D + oo] = w4.x; ldsW[(k2 + 1) * D + oo] = w4.y;
                ldsW[(k2 + 2) * D + oo] = w4.z; ldsW[(k2 + 3) * D + oo] = w4.w;
            }
        }
        __syncthreads();
#pragma unroll 4
        for (int k2 = 0; k2 < 64; ++k2) {
            const float4 wv = *(const float4*)&ldsW[k2 * D + 4 * og];
            const float4 xv = *(const float4*)&ldsE[kt * 64 + k2][4 * eg];
            const float wa[4] = {wv.x, wv.y, wv.z, wv.w};
            const float xa[4] = {xv.x, xv.y, xv.z, xv.w};
#pragma unroll
            for (int a = 0; a < 4; ++a)
#pragma unroll
                for (int c = 0; c < 4; ++c)
                    acc[a][c] = fmaf(xa[a], wa[c], acc[a][c]);
        }
    }
    const float4 bmv = *(const float4*)&bm[4 * og];
    const float4 g1v = *(const float4*)&g1[4 * og];
    const float4 b1v = *(const float4*)&b1[4 * og];
#pragma unroll
    for (int a = 0; a < 4; ++a) {
        acc[a][0] += bmv.x; acc[a][1] += bmv.y;
        acc[a][2] += bmv.z; acc[a][3] += bmv.w;
    }
    float mu[4], rs[4];
#pragma unroll
    for (int a = 0; a < 4; ++a) {
        float s = acc[a][0] + acc[a][1] + acc[a][2] + acc[a][3];
#pragma unroll
        for (int m = 16; m >= 1; m >>= 1) s += __shfl_xor(s, m, 64);
        mu[a] = s * (1.0f / 128.0f);
        const float d0 = acc[a][0] - mu[a], d1 = acc[a][1] - mu[a];
        const float d2 = acc[a][2] - mu[a], d3 = acc[a][3] - mu[a];
        float q = d0 * d0 + d1 * d1 + d2 * d2 + d3 * d3;
#pragma unroll
        for (int m = 16; m >= 1; m >>= 1) q += __shfl_xor(q, m, 64);
        rs[a] = rsqrtf(q * (1.0f / 128.0f) + EPS);
    }
#pragma unroll
    for (int a = 0; a < 4; ++a) {
        const int e = e0 + 4 * eg + a;
        const int r = receivers[e];
        float* dst = inbox + ((size_t)b * N_NODES + r) * D + 4 * og;
        atomicAdd(dst + 0, (acc[a][0] - mu[a]) * rs[a] * g1v.x + b1v.x);
        atomicAdd(dst + 1, (acc[a][1] - mu[a]) * rs[a] * g1v.y + b1v.y);
        atomicAdd(dst + 2, (acc[a][2] - mu[a]) * rs[a] * g1v.z + b1v.z);
        atomicAdd(dst + 3, (acc[a][3] - mu[a]) * rs[a] * g1v.w + b1v.w);
    }
}

__global__ __launch_bounds__(256, 2)
void node_kernel(const float* __restrict__ nodes,
                 const float* __restrict__ inbox,
                 const float* __restrict__ Wn,
                 const float* __restrict__ bn,
                 const float* __restrict__ g2,
                 const float* __restrict__ b2,
                 float* __restrict__ out) {
    __shared__ __align__(16) float ldsE[TWO_D][36];
    __shared__ __align__(16) float ldsW[64 * D];
    const int tid = threadIdx.x;
    const int b   = blockIdx.y;
    const int n0  = blockIdx.x * 32;
    {
        const int i = tid >> 3, q0 = tid & 7;
        int n = n0 + i;
        if (n >= N_NODES) n = N_NODES - 1;
        const float* rowN = nodes + ((size_t)b * N_NODES + n) * D;
        const float* rowI = inbox + ((size_t)b * N_NODES + n) * D;
#pragma unroll
        for (int j = 0; j < 8; ++j) {
            const int k = (j * 8 + q0) * 4;
            const float4 v = (k < D) ? *(const float4*)(rowN + k)
                                     : *(const float4*)(rowI + (k - D));
            ldsE[k + 0][i] = v.x; ldsE[k + 1][i] = v.y;
            ldsE[k + 2][i] = v.z; ldsE[k + 3][i] = v.w;
        }
    }
    float acc[4][4];
#pragma unroll
    for (int a = 0; a < 4; ++a)
#pragma unroll
        for (int c = 0; c < 4; ++c) acc[a][c] = 0.0f;
    const int og = tid & 31, eg = tid >> 5;
    for (int kt = 0; kt < 4; ++kt) {
        __syncthreads();
        {
            const int oo = tid >> 1, half = tid & 1;
            const float* wrow = Wn + oo * TWO_D + kt * 64 + half * 32;
#pragma unroll
            for (int j = 0; j < 8; ++j) {
                const float4 w4 = *(const float4*)(wrow + j * 4);
                const int k2 = half * 32 + j * 4;
                ldsW[(k2 + 0) * D + oo] = w4.x; ldsW[(k2 + 1) * D + oo] = w4.y;
                ldsW[(k2 + 2) * D + oo] = w4.z; ldsW[(k2 + 3) * D + oo] = w4.w;
            }
        }
        __syncthreads();
#pragma unroll 4
        for (int k2 = 0; k2 < 64; ++k2) {
            const float4 wv = *(const float4*)&ldsW[k2 * D + 4 * og];
            const float4 xv = *(const float4*)&ldsE[kt * 64 + k2][4 * eg];
            const float wa[4] = {wv.x, wv.y, wv.z, wv.w};
            const float xa[4] = {xv.x, xv.y, xv.z, xv.w};
#pragma unroll
            for (int a = 0; a < 4; ++a)
#pragma unroll
                for (int c = 0; c < 4; ++c)
                    acc[a][c] = fmaf(xa[a], wa[c], acc[a][c]);
        }
    }
    const float4 bnv = *(const float4*)&bn[4 * og];
    const float4 g2v = *(const float4*)&g2[4 * og];
    const float4 b2v = *(const float4*)&b2[4 * og];
#pragma unroll
    for (int a = 0; a < 4; ++a) {
        acc[a][0] += bnv.x; acc[a][1] += bnv.y;
        acc[a][2] += bnv.z; acc[a][3] += bnv.w;
    }
    float mu[4], rs[4];
#pragma unroll
    for (int a = 0; a < 4; ++a) {
        float s = acc[a][0] + acc[a][1] + acc[a][2] + acc[a][3];
#pragma unroll
        for (int m = 16; m >= 1; m >>= 1) s += __shfl_xor(s, m, 64);
        mu[a] = s * (1.0f / 128.0f);
        const float d0 = acc[a][0] - mu[a], d1 = acc[a][1] - mu[a];
        const float d2 = acc[a][2] - mu[a], d3 = acc[a][3] - mu[a];
        float q = d0 * d0 + d1 * d1 + d2 * d2 + d3 * d3;
#pragma unroll
        for (int m = 16; m >= 1; m >>= 1) q += __shfl_xor(q, m, 64);
        rs[a] = rsqrtf(q * (1.0f / 128.0f) + EPS);
    }
#pragma unroll
    for (int a = 0; a < 4; ++a) {
        const int n = n0 + 4 * eg + a;
        if (n < N_NODES) {
            float4 o4;
            o4.x = (acc[a][0] - mu[a]) * rs[a] * g2v.x + b2v.x;
            o4.y = (acc[a][1] - mu[a]) * rs[a] * g2v.y + b2v.y;
            o4.z = (acc[a][2] - mu[a]) * rs[a] * g2v.z + b2v.z;
            o4.w = (acc[a][3] - mu[a]) * rs[a] * g2v.w + b2v.w;
            *(float4*)(out + ((size_t)b * N_NODES + n) * D + 4 * og) = o4;
        }
    }
}

// ---------------------------------------------------------------------------
extern "C" void kernel_launch(void* const* d_in, const int* in_sizes, int n_in,
                              void* d_out, int out_size, void* d_ws, size_t ws_size,
                              hipStream_t stream) {
    const float* nodes     = (const float*)d_in[0];
    const float* Wm        = (const float*)d_in[1];
    const float* bm        = (const float*)d_in[2];
    const float* g1        = (const float*)d_in[3];
    const float* b1        = (const float*)d_in[4];
    const float* Wn        = (const float*)d_in[5];
    const float* bn        = (const float*)d_in[6];
    const float* g2        = (const float*)d_in[7];
    const float* b2        = (const float*)d_in[8];
    const int*   senders   = (const int*)d_in[9];
    const int*   receivers = (const int*)d_in[10];
    float*       out       = (float*)d_out;

    const long long inbox_n = (long long)BATCH * N_NODES * D;   // 10.24M floats
    // ws: [0,64K) img_m | [64K,128K) img_n | [128K,+720K) sort | [1M,+41MB) inbox
    const size_t SCRATCH_NEED = 131072 + 720128;

    if (d_ws != nullptr && ws_size >= SCRATCH_NEED) {
        unsigned char* wsb  = (unsigned char*)d_ws;
        unsigned char* wimg = wsb;                 // img_m @0, img_n @65536
        int* ints   = (int*)(wsb + 131072);
        int* counts = ints;            // 10000 (16B aligned)
        int* cursor = ints + 10016;    // 10000
        int* perm   = ints + 20032;    // 160000
        float* inbox = (ws_size >= (size_t)1048576 + (size_t)inbox_n * 4)
                           ? (float*)(wsb + 1048576) : out;

        zero_kernel<<<dim3(10),   dim3(256), 0, stream>>>((float4*)counts, 2500);
        zero_kernel<<<dim3(2048), dim3(256), 0, stream>>>((float4*)inbox, inbox_n / 4);
        prep_w<<<dim3(16), dim3(256), 0, stream>>>(Wm, Wn, wimg);
        hist_kernel<<<dim3(625), dim3(256), 0, stream>>>(receivers, counts);
        scan_kernel<<<dim3(1), dim3(1024), 0, stream>>>(counts, cursor);
        scatter_kernel<<<dim3(625), dim3(256), 0, stream>>>(receivers, cursor, perm);

        edge_mfma<<<dim3(N_EDGES / ETILE, BATCH), dim3(128), 0, stream>>>(
            nodes, wimg, bm, g1, b1, senders, receivers, perm, inbox);

        node_mfma<<<dim3((N_NODES + ETILE - 1) / ETILE, BATCH), dim3(128), 0, stream>>>(
            nodes, inbox, wimg + 65536, bn, g2, b2, out);
    } else {
        // proven fp32 fallback (no workspace needed)
        float* inbox = out;
        zero_kernel<<<dim3(2048), dim3(256), 0, stream>>>((float4*)inbox, inbox_n / 4);
        edge_kernel<<<dim3(N_EDGES / 32, BATCH), dim3(256), 0, stream>>>(
            nodes, Wm, bm, g1, b1, senders, receivers, inbox);
        node_kernel<<<dim3((N_NODES + 31) / 32, BATCH), dim3(256), 0, stream>>>(
            nodes, inbox, Wn, bn, g2, b2, out);
    }
}

// Round 6
// 460.947 us; speedup vs baseline: 5.4384x; 1.1535x over previous
//
#include <hip/hip_runtime.h>

#define N_NODES 10000
#define N_EDGES 160000
#define BATCH   8
#define D       128
#define TWO_D   256
#define EPS     1e-5f
#define ETILE   32
#define TPB_E   8     // edge tiles per block (persistent loop)
#define TPB_N   8     // node tiles per block

typedef _Float16 f16x8  __attribute__((ext_vector_type(8)));
typedef float    f32x16 __attribute__((ext_vector_type(16)));

// ---------------- generic zero ----------------
__global__ void zero_kernel(float4* __restrict__ p, long long n4) {
    long long idx    = (long long)blockIdx.x * blockDim.x + threadIdx.x;
    long long stride = (long long)gridDim.x * blockDim.x;
    const float4 z = {0.f, 0.f, 0.f, 0.f};
    for (long long i = idx; i < n4; i += stride) p[i] = z;
}

// ---------------- W prep: f16 images in B-fragment order ----------------
// img_m[g*128 + o] (16B = 8 f16) = Wm[o][8g .. 8g+7],  g in [0,32)  (64 KB)
// img_n at +65536 likewise for Wn.
__global__ void prep_w(const float* __restrict__ Wm, const float* __restrict__ Wn,
                       unsigned char* __restrict__ img) {
    int t = blockIdx.x * blockDim.x + threadIdx.x;
    if (t >= 4096) return;
    int g = t >> 7, o = t & 127;
    f16x8 vm, vn;
#pragma unroll
    for (int j = 0; j < 8; ++j) {
        vm[j] = (_Float16)Wm[o * TWO_D + 8 * g + j];
        vn[j] = (_Float16)Wn[o * TWO_D + 8 * g + j];
    }
    ((f16x8*)img)[t]           = vm;
    ((f16x8*)(img + 65536))[t] = vn;
}

// ---------------- counting sort of edges by receiver (proven) ----------
__global__ void hist_kernel(const int* __restrict__ recv, int* __restrict__ counts) {
    int e = blockIdx.x * blockDim.x + threadIdx.x;
    if (e < N_EDGES) atomicAdd(&counts[recv[e]], 1);
}

__global__ __launch_bounds__(1024)
void scan_kernel(const int* __restrict__ counts, int* __restrict__ cursor) {
    __shared__ int tmp[1024];
    int t = threadIdx.x;
    int local[10];
    int s = 0;
#pragma unroll
    for (int j = 0; j < 10; ++j) {
        int idx = t * 10 + j;
        int v = (idx < N_NODES) ? counts[idx] : 0;
        local[j] = s; s += v;
    }
    tmp[t] = s; __syncthreads();
    for (int off = 1; off < 1024; off <<= 1) {
        int v = tmp[t];
        int add = (t >= off) ? tmp[t - off] : 0;
        __syncthreads();
        tmp[t] = v + add;
        __syncthreads();
    }
    int base = (t > 0) ? tmp[t - 1] : 0;
#pragma unroll
    for (int j = 0; j < 10; ++j) {
        int idx = t * 10 + j;
        if (idx < N_NODES) cursor[idx] = base + local[j];
    }
}

__global__ void scatter_kernel(const int* __restrict__ recv, int* __restrict__ cursor,
                               int* __restrict__ perm) {
    int e = blockIdx.x * blockDim.x + threadIdx.x;
    if (e < N_EDGES) {
        int p = atomicAdd(&cursor[recv[e]], 1);
        perm[p] = e;
    }
}

// ---------------- MFMA edge kernel v3 (persistent) ----------------
// 256 threads = 4 waves. Wave w owns output col-tile [32w, 32w+32): 16 W f16
// fragments in REGISTERS, loaded ONCE per block (live across the tile loop ->
// compiler must keep them resident). Block loops over TPB_E consecutive
// receiver-sorted 32-edge tiles.
// X staging map: i = tid&31 (edge slot), q8 = tid>>5 (k-32-chunk). Per write
// instruction each wave-quarter hits 256B contiguous LDS -> conflict-free.
// k-loop: 16 ksteps x (2 ds_read_b128 + 2 MFMA) per wave, no mid-loop barriers.
// LN: single-pass (E[x2]-mu2) over msg transpose; scatter = sorted run-merge.
__global__ __launch_bounds__(256, 2)
void edge_mfma(const float* __restrict__ nodes,
               const unsigned char* __restrict__ wimg,
               const float* __restrict__ bm,
               const float* __restrict__ g1,
               const float* __restrict__ b1,
               const int*   __restrict__ senders,
               const int*   __restrict__ receivers,
               const int*   __restrict__ perm,
               float* __restrict__ inbox) {
    // Xh [0,16K), Xl [16K,32K); msg fp32[32][132] overlays @16384..33280
    __shared__ __align__(16) unsigned char s_lds[33280];
    __shared__ int   s_recv[ETILE];
    __shared__ float s_mu[ETILE];
    __shared__ float s_rs[ETILE];

    const int tid    = threadIdx.x;
    const int b      = blockIdx.y;
    const int w      = tid >> 6;
    const int l      = tid & 63;
    const int lane31 = l & 31;
    const int hiG    = l >> 5;
    const int o      = w * 32 + lane31;       // this lane's output column

    // ---- W fragments -> registers, ONCE per block ----
    f16x8 wf[16];
    {
        const f16x8* img = (const f16x8*)wimg;
#pragma unroll
        for (int ks = 0; ks < 16; ++ks)
            wf[ks] = img[(2 * ks + hiG) * 128 + o];
    }
    const float bmv = bm[o];
    const int   col  = tid & 127;
    const int   half = tid >> 7;
    const float gv = g1[col], bv = b1[col];
    float* const abase = inbox + (size_t)b * N_NODES * D + col;

    const int i  = tid & 31;   // edge slot
    const int q8 = tid >> 5;   // k chunk [32*q8, 32*q8+32) of the 256-k row
    f16x8* const Xh  = (f16x8*)s_lds;
    f16x8* const Xl  = (f16x8*)(s_lds + 16384);
    float* const msg = (float*)(s_lds + 16384);

    for (int it = 0; it < TPB_E; ++it) {
        const int e0 = (blockIdx.x * TPB_E + it) * ETILE;

        // ---- stage: gather + f16 hi/lo split, conflict-free layout ----
        {
            const int pe = perm[e0 + i];
            const int r  = (q8 < 4) ? receivers[pe] : senders[pe];
            if (q8 == 0) s_recv[i] = r;
            const float* row = nodes + ((size_t)b * N_NODES + r) * D + (q8 & 3) * 32;
#pragma unroll
            for (int j = 0; j < 4; ++j) {
                const float4 va = *(const float4*)(row + 8 * j);
                const float4 vb = *(const float4*)(row + 8 * j + 4);
                const float xs[8] = {va.x, va.y, va.z, va.w, vb.x, vb.y, vb.z, vb.w};
                f16x8 h, lo;
#pragma unroll
                for (int u = 0; u < 8; ++u) {
                    h[u]  = (_Float16)xs[u];
                    lo[u] = (_Float16)(xs[u] - (float)h[u]);
                }
                const int g = 4 * q8 + j;
                Xh[g * 32 + i] = h;
                Xl[g * 32 + i] = lo;
            }
        }
        __syncthreads();

        // ---- k-loop: pure LDS-read + MFMA ----
        f32x16 acc;
#pragma unroll
        for (int r = 0; r < 16; ++r) acc[r] = 0.f;
#pragma unroll
        for (int ks = 0; ks < 16; ++ks) {
            const f16x8 ah = Xh[(2 * ks + hiG) * 32 + lane31];
            const f16x8 al = Xl[(2 * ks + hiG) * 32 + lane31];
            acc = __builtin_amdgcn_mfma_f32_32x32x16_f16(ah, wf[ks], acc, 0, 0, 0);
            acc = __builtin_amdgcn_mfma_f32_32x32x16_f16(al, wf[ks], acc, 0, 0, 0);
        }
        __syncthreads();   // X reads done; msg overlays Xl

        // ---- bias + raw messages -> msg[32][132] ----
#pragma unroll
        for (int r = 0; r < 16; ++r) {
            const int m = (r & 3) + 8 * (r >> 2) + 4 * hiG;
            msg[m * 132 + o] = acc[r] + bmv;
        }
        __syncthreads();

        // ---- LN stats, single pass (8 threads per row) ----
        {
            const int m = tid >> 3, c0 = tid & 7;
            float s = 0.f, s2 = 0.f;
#pragma unroll
            for (int i2 = 0; i2 < 16; ++i2) {
                const float v = msg[m * 132 + c0 + 8 * i2];
                s += v; s2 += v * v;
            }
            s  += __shfl_xor(s, 1, 64);  s  += __shfl_xor(s, 2, 64);  s  += __shfl_xor(s, 4, 64);
            s2 += __shfl_xor(s2, 1, 64); s2 += __shfl_xor(s2, 2, 64); s2 += __shfl_xor(s2, 4, 64);
            if (c0 == 0) {
                const float mu  = s * (1.f / 128.f);
                const float var = s2 * (1.f / 128.f) - mu * mu;
                s_mu[m] = mu;
                s_rs[m] = rsqrtf(var + EPS);
            }
        }
        __syncthreads();

        // ---- scatter: inline LN + run-merge over sorted receivers ----
        {
            int prev = -1; float accu = 0.f;
#pragma unroll
            for (int e = 0; e < 16; ++e) {
                const int ee = half * 16 + e;
                const int r  = s_recv[ee];
                const float val = (msg[ee * 132 + col] - s_mu[ee]) * s_rs[ee] * gv + bv;
                if (r != prev) {
                    if (prev >= 0) atomicAdd(abase + (size_t)prev * D, accu);
                    prev = r; accu = val;
                } else {
                    accu += val;
                }
            }
            if (prev >= 0) atomicAdd(abase + (size_t)prev * D, accu);
        }
        __syncthreads();   // protect X/msg before next tile's stage
    }
}

// ---------------- MFMA node kernel v3 (persistent, same template) --------
__global__ __launch_bounds__(256, 2)
void node_mfma(const float* __restrict__ nodes,
               const float* __restrict__ inbox,
               const unsigned char* __restrict__ wimg,
               const float* __restrict__ bn,
               const float* __restrict__ g2,
               const float* __restrict__ b2,
               float* __restrict__ out) {
    __shared__ __align__(16) unsigned char s_lds[33280];
    __shared__ float s_mu[ETILE];
    __shared__ float s_rs[ETILE];

    const int tid    = threadIdx.x;
    const int b      = blockIdx.y;
    const int w      = tid >> 6;
    const int l      = tid & 63;
    const int lane31 = l & 31;
    const int hiG    = l >> 5;
    const int o      = w * 32 + lane31;

    f16x8 wf[16];
    {
        const f16x8* img = (const f16x8*)wimg;
#pragma unroll
        for (int ks = 0; ks < 16; ++ks)
            wf[ks] = img[(2 * ks + hiG) * 128 + o];
    }
    const float bnv = bn[o];
    const int   col  = tid & 127;
    const int   half = tid >> 7;
    const float gv = g2[col], bv = b2[col];

    const int i  = tid & 31;
    const int q8 = tid >> 5;
    f16x8* const Xh  = (f16x8*)s_lds;
    f16x8* const Xl  = (f16x8*)(s_lds + 16384);
    float* const msg = (float*)(s_lds + 16384);

    const int NTILES = (N_NODES + ETILE - 1) / ETILE;   // 313

    for (int it = 0; it < TPB_N; ++it) {
        const int tile = blockIdx.x * TPB_N + it;
        if (tile >= NTILES) break;                       // uniform per block
        const int n0 = tile * ETILE;

        {
            int n = n0 + i;
            if (n >= N_NODES) n = N_NODES - 1;           // clamp loads
            const float* row = (q8 < 4)
                ? (nodes + ((size_t)b * N_NODES + n) * D + (q8 & 3) * 32)
                : (inbox + ((size_t)b * N_NODES + n) * D + (q8 & 3) * 32);
#pragma unroll
            for (int j = 0; j < 4; ++j) {
                const float4 va = *(const float4*)(row + 8 * j);
                const float4 vb = *(const float4*)(row + 8 * j + 4);
                const float xs[8] = {va.x, va.y, va.z, va.w, vb.x, vb.y, vb.z, vb.w};
                f16x8 h, lo;
#pragma unroll
                for (int u = 0; u < 8; ++u) {
                    h[u]  = (_Float16)xs[u];
                    lo[u] = (_Float16)(xs[u] - (float)h[u]);
                }
                const int g = 4 * q8 + j;
                Xh[g * 32 + i] = h;
                Xl[g * 32 + i] = lo;
            }
        }
        __syncthreads();

        f32x16 acc;
#pragma unroll
        for (int r = 0; r < 16; ++r) acc[r] = 0.f;
#pragma unroll
        for (int ks = 0; ks < 16; ++ks) {
            const f16x8 ah = Xh[(2 * ks + hiG) * 32 + lane31];
            const f16x8 al = Xl[(2 * ks + hiG) * 32 + lane31];
            acc = __builtin_amdgcn_mfma_f32_32x32x16_f16(ah, wf[ks], acc, 0, 0, 0);
            acc = __builtin_amdgcn_mfma_f32_32x32x16_f16(al, wf[ks], acc, 0, 0, 0);
        }
        __syncthreads();

#pragma unroll
        for (int r = 0; r < 16; ++r) {
            const int m = (r & 3) + 8 * (r >> 2) + 4 * hiG;
            msg[m * 132 + o] = acc[r] + bnv;
        }
        __syncthreads();

        {
            const int m = tid >> 3, c0 = tid & 7;
            float s = 0.f, s2 = 0.f;
#pragma unroll
            for (int i2 = 0; i2 < 16; ++i2) {
                const float v = msg[m * 132 + c0 + 8 * i2];
                s += v; s2 += v * v;
            }
            s  += __shfl_xor(s, 1, 64);  s  += __shfl_xor(s, 2, 64);  s  += __shfl_xor(s, 4, 64);
            s2 += __shfl_xor(s2, 1, 64); s2 += __shfl_xor(s2, 2, 64); s2 += __shfl_xor(s2, 4, 64);
            if (c0 == 0) {
                const float mu  = s * (1.f / 128.f);
                const float var = s2 * (1.f / 128.f) - mu * mu;
                s_mu[m] = mu;
                s_rs[m] = rsqrtf(var + EPS);
            }
        }
        __syncthreads();

        {
#pragma unroll
            for (int e = 0; e < 16; ++e) {
                const int ee = half * 16 + e;
                const int n  = n0 + ee;
                if (n < N_NODES) {
                    out[((size_t)b * N_NODES + n) * D + col] =
                        (msg[ee * 132 + col] - s_mu[ee]) * s_rs[ee] * gv + bv;
                }
            }
        }
        __syncthreads();
    }
}

// ---------------- fp32 fallback kernels (proven R2, no workspace) ---------
__global__ __launch_bounds__(256, 2)
void edge_kernel(const float* __restrict__ nodes,
                 const float* __restrict__ Wm,
                 const float* __restrict__ bm,
                 const float* __restrict__ g1,
                 const float* __restrict__ b1,
                 const int*   __restrict__ senders,
                 const int*   __restrict__ receivers,
                 float* __restrict__ inbox) {
    __shared__ __align__(16) float ldsE[TWO_D][36];
    __shared__ __align__(16) float ldsW[64 * D];
    const int tid = threadIdx.x;
    const int b   = blockIdx.y;
    const int e0  = blockIdx.x * 32;
    const float* nb = nodes + (size_t)b * N_NODES * D;
    {
        const int i = tid >> 3, q0 = tid & 7, e = e0 + i;
        const float* rowR = nb + (size_t)receivers[e] * D;
        const float* rowS = nb + (size_t)senders[e] * D;
#pragma unroll
        for (int j = 0; j < 8; ++j) {
            const int k = (j * 8 + q0) * 4;
            const float4 v = (k < D) ? *(const float4*)(rowR + k)
                                     : *(const float4*)(rowS + (k - D));
            ldsE[k + 0][i] = v.x; ldsE[k + 1][i] = v.y;
            ldsE[k + 2][i] = v.z; ldsE[k + 3][i] = v.w;
        }
    }
    float acc[4][4];
#pragma unroll
    for (int a = 0; a < 4; ++a)
#pragma unroll
        for (int c = 0; c < 4; ++c) acc[a][c] = 0.0f;
    const int og = tid & 31, eg = tid >> 5;
    for (int kt = 0; kt < 4; ++kt) {
        __syncthreads();
        {
            const int oo = tid >> 1, half = tid & 1;
            const float* wrow = Wm + oo * TWO_D + kt * 64 + half * 32;
#pragma unroll
            for (int j = 0; j < 8; ++j) {
                const float4 w4 = *(const float4*)(wrow + j * 4);
                const int k2 = half * 32 + j * 4;
                ldsW[(k2 + 0) * D + oo] = w4.x; ldsW[(k2 + 1) * D + oo] = w4.y;
                ldsW[(k2 + 2) * D + oo] = w4.z; ldsW[(k2 + 3) * D + oo] = w4.w;
            }
        }
        __syncthreads();
#pragma unroll 4
        for (int k2 = 0; k2 < 64; ++k2) {
            const float4 wv = *(const float4*)&ldsW[k2 * D + 4 * og];
            const float4 xv = *(const float4*)&ldsE[kt * 64 + k2][4 * eg];
            const float wa[4] = {wv.x, wv.y, wv.z, wv.w};
            const float xa[4] = {xv.x, xv.y, xv.z, xv.w};
#pragma unroll
            for (int a = 0; a < 4; ++a)
#pragma unroll
                for (int c = 0; c < 4; ++c)
                    acc[a][c] = fmaf(xa[a], wa[c], acc[a][c]);
        }
    }
    const float4 bmv = *(const float4*)&bm[4 * og];
    const float4 g1v = *(const float4*)&g1[4 * og];
    const float4 b1v = *(const float4*)&b1[4 * og];
#pragma unroll
    for (int a = 0; a < 4; ++a) {
        acc[a][0] += bmv.x; acc[a][1] += bmv.y;
        acc[a][2] += bmv.z; acc[a][3] += bmv.w;
    }
    float mu[4], rs[4];
#pragma unroll
    for (int a = 0; a < 4; ++a) {
        float s = acc[a][0] + acc[a][1] + acc[a][2] + acc[a][3];
#pragma unroll
        for (int m = 16; m >= 1; m >>= 1) s += __shfl_xor(s, m, 64);
        mu[a] = s * (1.0f / 128.0f);
        const float d0 = acc[a][0] - mu[a], d1 = acc[a][1] - mu[a];
        const float d2 = acc[a][2] - mu[a], d3 = acc[a][3] - mu[a];
        float q = d0 * d0 + d1 * d1 + d2 * d2 + d3 * d3;
#pragma unroll
        for (int m = 16; m >= 1; m >>= 1) q += __shfl_xor(q, m, 64);
        rs[a] = rsqrtf(q * (1.0f / 128.0f) + EPS);
    }
#pragma unroll
    for (int a = 0; a < 4; ++a) {
        const int e = e0 + 4 * eg + a;
        const int r = receivers[e];
        float* dst = inbox + ((size_t)b * N_NODES + r) * D + 4 * og;
        atomicAdd(dst + 0, (acc[a][0] - mu[a]) * rs[a] * g1v.x + b1v.x);
        atomicAdd(dst + 1, (acc[a][1] - mu[a]) * rs[a] * g1v.y + b1v.y);
        atomicAdd(dst + 2, (acc[a][2] - mu[a]) * rs[a] * g1v.z + b1v.z);
        atomicAdd(dst + 3, (acc[a][3] - mu[a]) * rs[a] * g1v.w + b1v.w);
    }
}

__global__ __launch_bounds__(256, 2)
void node_kernel(const float* __restrict__ nodes,
                 const float* __restrict__ inbox,
                 const float* __restrict__ Wn,
                 const float* __restrict__ bn,
                 const float* __restrict__ g2,
                 const float* __restrict__ b2,
                 float* __restrict__ out) {
    __shared__ __align__(16) float ldsE[TWO_D][36];
    __shared__ __align__(16) float ldsW[64 * D];
    const int tid = threadIdx.x;
    const int b   = blockIdx.y;
    const int n0  = blockIdx.x * 32;
    {
        const int i = tid >> 3, q0 = tid & 7;
        int n = n0 + i;
        if (n >= N_NODES) n = N_NODES - 1;
        const float* rowN = nodes + ((size_t)b * N_NODES + n) * D;
        const float* rowI = inbox + ((size_t)b * N_NODES + n) * D;
#pragma unroll
        for (int j = 0; j < 8; ++j) {
            const int k = (j * 8 + q0) * 4;
            const float4 v = (k < D) ? *(const float4*)(rowN + k)
                                     : *(const float4*)(rowI + (k - D));
            ldsE[k + 0][i] = v.x; ldsE[k + 1][i] = v.y;
            ldsE[k + 2][i] = v.z; ldsE[k + 3][i] = v.w;
        }
    }
    float acc[4][4];
#pragma unroll
    for (int a = 0; a < 4; ++a)
#pragma unroll
        for (int c = 0; c < 4; ++c) acc[a][c] = 0.0f;
    const int og = tid & 31, eg = tid >> 5;
    for (int kt = 0; kt < 4; ++kt) {
        __syncthreads();
        {
            const int oo = tid >> 1, half = tid & 1;
            const float* wrow = Wn + oo * TWO_D + kt * 64 + half * 32;
#pragma unroll
            for (int j = 0; j < 8; ++j) {
                const float4 w4 = *(const float4*)(wrow + j * 4);
                const int k2 = half * 32 + j * 4;
                ldsW[(k2 + 0) * D + oo] = w4.x; ldsW[(k2 + 1) * D + oo] = w4.y;
                ldsW[(k2 + 2) * D + oo] = w4.z; ldsW[(k2 + 3) * D + oo] = w4.w;
            }
        }
        __syncthreads();
#pragma unroll 4
        for (int k2 = 0; k2 < 64; ++k2) {
            const float4 wv = *(const float4*)&ldsW[k2 * D + 4 * og];
            const float4 xv = *(const float4*)&ldsE[kt * 64 + k2][4 * eg];
            const float wa[4] = {wv.x, wv.y, wv.z, wv.w};
            const float xa[4] = {xv.x, xv.y, xv.z, xv.w};
#pragma unroll
            for (int a = 0; a < 4; ++a)
#pragma unroll
                for (int c = 0; c < 4; ++c)
                    acc[a][c] = fmaf(xa[a], wa[c], acc[a][c]);
        }
    }
    const float4 bnv = *(const float4*)&bn[4 * og];
    const float4 g2v = *(const float4*)&g2[4 * og];
    const float4 b2v = *(const float4*)&b2[4 * og];
#pragma unroll
    for (int a = 0; a < 4; ++a) {
        acc[a][0] += bnv.x; acc[a][1] += bnv.y;
        acc[a][2] += bnv.z; acc[a][3] += bnv.w;
    }
    float mu[4], rs[4];
#pragma unroll
    for (int a = 0; a < 4; ++a) {
        float s = acc[a][0] + acc[a][1] + acc[a][2] + acc[a][3];
#pragma unroll
        for (int m = 16; m >= 1; m >>= 1) s += __shfl_xor(s, m, 64);
        mu[a] = s * (1.0f / 128.0f);
        const float d0 = acc[a][0] - mu[a], d1 = acc[a][1] - mu[a];
        const float d2 = acc[a][2] - mu[a], d3 = acc[a][3] - mu[a];
        float q = d0 * d0 + d1 * d1 + d2 * d2 + d3 * d3;
#pragma unroll
        for (int m = 16; m >= 1; m >>= 1) q += __shfl_xor(q, m, 64);
        rs[a] = rsqrtf(q * (1.0f / 128.0f) + EPS);
    }
#pragma unroll
    for (int a = 0; a < 4; ++a) {
        const int n = n0 + 4 * eg + a;
        if (n < N_NODES) {
            float4 o4;
            o4.x = (acc[a][0] - mu[a]) * rs[a] * g2v.x + b2v.x;
            o4.y = (acc[a][1] - mu[a]) * rs[a] * g2v.y + b2v.y;
            o4.z = (acc[a][2] - mu[a]) * rs[a] * g2v.z + b2v.z;
            o4.w = (acc[a][3] - mu[a]) * rs[a] * g2v.w + b2v.w;
            *(float4*)(out + ((size_t)b * N_NODES + n) * D + 4 * og) = o4;
        }
    }
}

// ---------------------------------------------------------------------------
extern "C" void kernel_launch(void* const* d_in, const int* in_sizes, int n_in,
                              void* d_out, int out_size, void* d_ws, size_t ws_size,
                              hipStream_t stream) {
    const float* nodes     = (const float*)d_in[0];
    const float* Wm        = (const float*)d_in[1];
    const float* bm        = (const float*)d_in[2];
    const float* g1        = (const float*)d_in[3];
    const float* b1        = (const float*)d_in[4];
    const float* Wn        = (const float*)d_in[5];
    const float* bn        = (const float*)d_in[6];
    const float* g2        = (const float*)d_in[7];
    const float* b2        = (const float*)d_in[8];
    const int*   senders   = (const int*)d_in[9];
    const int*   receivers = (const int*)d_in[10];
    float*       out       = (float*)d_out;

    const long long inbox_n = (long long)BATCH * N_NODES * D;   // 10.24M floats
    // ws: [0,64K) img_m | [64K,128K) img_n | [128K,+720K) sort | [1M,+41MB) inbox
    const size_t SCRATCH_NEED = 131072 + 720128;

    if (d_ws != nullptr && ws_size >= SCRATCH_NEED) {
        unsigned char* wsb  = (unsigned char*)d_ws;
        unsigned char* wimg = wsb;                 // img_m @0, img_n @65536
        int* ints   = (int*)(wsb + 131072);
        int* counts = ints;            // 10000 (16B aligned)
        int* cursor = ints + 10016;    // 10000
        int* perm   = ints + 20032;    // 160000
        float* inbox = (ws_size >= (size_t)1048576 + (size_t)inbox_n * 4)
                           ? (float*)(wsb + 1048576) : out;

        zero_kernel<<<dim3(10),   dim3(256), 0, stream>>>((float4*)counts, 2500);
        zero_kernel<<<dim3(2048), dim3(256), 0, stream>>>((float4*)inbox, inbox_n / 4);
        prep_w<<<dim3(16), dim3(256), 0, stream>>>(Wm, Wn, wimg);
        hist_kernel<<<dim3(625), dim3(256), 0, stream>>>(receivers, counts);
        scan_kernel<<<dim3(1), dim3(1024), 0, stream>>>(counts, cursor);
        scatter_kernel<<<dim3(625), dim3(256), 0, stream>>>(receivers, cursor, perm);

        // 5000 edge tiles = 625 blocks x TPB_E(8) tiles, per batch
        edge_mfma<<<dim3(N_EDGES / ETILE / TPB_E, BATCH), dim3(256), 0, stream>>>(
            nodes, wimg, bm, g1, b1, senders, receivers, perm, inbox);

        // 313 node tiles -> 40 blocks x 8 tiles (guarded), per batch
        const int ntiles = (N_NODES + ETILE - 1) / ETILE;
        node_mfma<<<dim3((ntiles + TPB_N - 1) / TPB_N, BATCH), dim3(256), 0, stream>>>(
            nodes, inbox, wimg + 65536, bn, g2, b2, out);
    } else {
        // proven fp32 fallback (no workspace needed)
        float* inbox = out;
        zero_kernel<<<dim3(2048), dim3(256), 0, stream>>>((float4*)inbox, inbox_n / 4);
        edge_kernel<<<dim3(N_EDGES / 32, BATCH), dim3(256), 0, stream>>>(
            nodes, Wm, bm, g1, b1, senders, receivers, inbox);
        node_kernel<<<dim3((N_NODES + 31) / 32, BATCH), dim3(256), 0, stream>>>(
            nodes, inbox, Wn, bn, g2, b2, out);
    }
}

// Round 9
// 421.988 us; speedup vs baseline: 5.9405x; 1.0923x over previous
//
#include <hip/hip_runtime.h>

#define N_NODES 10000
#define N_EDGES 160000
#define BATCH   8
#define D       128
#define TWO_D   256
#define EPS     1e-5f
#define ETILE   32
#define TPB_E   8     // edge tiles per block (persistent loop)
#define TPB_N   8     // node tiles per block

typedef _Float16 f16x8  __attribute__((ext_vector_type(8)));
typedef float    f32x16 __attribute__((ext_vector_type(16)));
typedef int      intx4  __attribute__((ext_vector_type(4)));

// ---------------- generic zero ----------------
__global__ void zero_kernel(float4* __restrict__ p, long long n4) {
    long long idx    = (long long)blockIdx.x * blockDim.x + threadIdx.x;
    long long stride = (long long)gridDim.x * blockDim.x;
    const float4 z = {0.f, 0.f, 0.f, 0.f};
    for (long long i = idx; i < n4; i += stride) p[i] = z;
}

// ---------------- W prep: f16 images in B-fragment order ----------------
// img_m[g*128 + o] (16B = 8 f16) = Wm[o][8g .. 8g+7],  g in [0,32)  (64 KB)
// img_n at +65536 likewise for Wn.
__global__ void prep_w(const float* __restrict__ Wm, const float* __restrict__ Wn,
                       unsigned char* __restrict__ img) {
    int t = blockIdx.x * blockDim.x + threadIdx.x;
    if (t >= 4096) return;
    int g = t >> 7, o = t & 127;
    f16x8 vm, vn;
#pragma unroll
    for (int j = 0; j < 8; ++j) {
        vm[j] = (_Float16)Wm[o * TWO_D + 8 * g + j];
        vn[j] = (_Float16)Wn[o * TWO_D + 8 * g + j];
    }
    ((f16x8*)img)[t]           = vm;
    ((f16x8*)(img + 65536))[t] = vn;
}

// ---------------- counting sort of edges by receiver (proven) ----------
__global__ void hist_kernel(const int* __restrict__ recv, int* __restrict__ counts) {
    int e = blockIdx.x * blockDim.x + threadIdx.x;
    if (e < N_EDGES) atomicAdd(&counts[recv[e]], 1);
}

__global__ __launch_bounds__(1024)
void scan_kernel(const int* __restrict__ counts, int* __restrict__ cursor) {
    __shared__ int tmp[1024];
    int t = threadIdx.x;
    int local[10];
    int s = 0;
#pragma unroll
    for (int j = 0; j < 10; ++j) {
        int idx = t * 10 + j;
        int v = (idx < N_NODES) ? counts[idx] : 0;
        local[j] = s; s += v;
    }
    tmp[t] = s; __syncthreads();
    for (int off = 1; off < 1024; off <<= 1) {
        int v = tmp[t];
        int add = (t >= off) ? tmp[t - off] : 0;
        __syncthreads();
        tmp[t] = v + add;
        __syncthreads();
    }
    int base = (t > 0) ? tmp[t - 1] : 0;
#pragma unroll
    for (int j = 0; j < 10; ++j) {
        int idx = t * 10 + j;
        if (idx < N_NODES) cursor[idx] = base + local[j];
    }
}

__global__ void scatter_kernel(const int* __restrict__ recv, int* __restrict__ cursor,
                               int* __restrict__ perm) {
    int e = blockIdx.x * blockDim.x + threadIdx.x;
    if (e < N_EDGES) {
        int p = atomicAdd(&cursor[recv[e]], 1);
        perm[p] = e;
    }
}

// ---------------- MFMA edge kernel v4 (persistent, W reg-pinned, XCD) ----
// 1-D grid 5000 blocks; batch = bid & 7 (XCD-pinned under round-robin
// dispatch -> each XCD L2 caches ONE batch's nodes+inbox, ~10 MB).
// 256 threads = 4 waves. Wave w owns output col-tile [32w,32w+32): 16 W f16
// fragments loaded ONCE and PINNED in VGPRs via asm (compiler cannot sink
// the loads back into the loop). Block loops over TPB_E receiver-sorted
// 32-edge tiles. X: f16 hi/lo split in conflict-free [g][row] LDS layout.
__global__ __launch_bounds__(256, 4)
void edge_mfma(const float* __restrict__ nodes,
               const unsigned char* __restrict__ wimg,
               const float* __restrict__ bm,
               const float* __restrict__ g1,
               const float* __restrict__ b1,
               const int*   __restrict__ senders,
               const int*   __restrict__ receivers,
               const int*   __restrict__ perm,
               float* __restrict__ inbox) {
    // Xh [0,16K), Xl [16K,32K); msg fp32[32][132] overlays @16384..33280
    __shared__ __align__(16) unsigned char s_lds[33280];
    __shared__ int   s_recv[ETILE];
    __shared__ float s_mu[ETILE];
    __shared__ float s_rs[ETILE];

    const int tid    = threadIdx.x;
    const int b      = blockIdx.x & 7;          // batch == XCD (round-robin)
    const int grp    = blockIdx.x >> 3;         // tile group within batch
    const int w      = tid >> 6;
    const int l      = tid & 63;
    const int lane31 = l & 31;
    const int hiG    = l >> 5;
    const int o      = w * 32 + lane31;         // this lane's output column

    // ---- W fragments -> registers, ONCE, pinned ----
    intx4 wfi[16];
    {
        const intx4* img = (const intx4*)wimg;
#pragma unroll
        for (int ks = 0; ks < 16; ++ks)
            wfi[ks] = img[(2 * ks + hiG) * 128 + o];
#pragma unroll
        for (int ks = 0; ks < 16; ++ks)
            asm volatile("" : "+v"(wfi[ks]));   // opaque def: must stay in VGPRs
    }
    const float bmv = bm[o];
    const int   col  = tid & 127;
    const int   half = tid >> 7;
    const float gv = g1[col], bv = b1[col];
    float* const abase = inbox + (size_t)b * N_NODES * D + col;

    const int i  = tid & 31;   // edge slot
    const int q8 = tid >> 5;   // k chunk [32*q8, 32*q8+32)
    f16x8* const Xh  = (f16x8*)s_lds;
    f16x8* const Xl  = (f16x8*)(s_lds + 16384);
    float* const msg = (float*)(s_lds + 16384);

    for (int it = 0; it < TPB_E; ++it) {
        const int e0 = (grp * TPB_E + it) * ETILE;

        // ---- stage: gather + f16 hi/lo split, conflict-free layout ----
        {
            const int pe = perm[e0 + i];
            const int r  = (q8 < 4) ? receivers[pe] : senders[pe];
            if (q8 == 0) s_recv[i] = r;
            const float* row = nodes + ((size_t)b * N_NODES + r) * D + (q8 & 3) * 32;
#pragma unroll
            for (int j = 0; j < 4; ++j) {
                const float4 va = *(const float4*)(row + 8 * j);
                const float4 vb = *(const float4*)(row + 8 * j + 4);
                const float xs[8] = {va.x, va.y, va.z, va.w, vb.x, vb.y, vb.z, vb.w};
                f16x8 h, lo;
#pragma unroll
                for (int u = 0; u < 8; ++u) {
                    h[u]  = (_Float16)xs[u];
                    lo[u] = (_Float16)(xs[u] - (float)h[u]);
                }
                const int g = 4 * q8 + j;
                Xh[g * 32 + i] = h;
                Xl[g * 32 + i] = lo;
            }
        }
        __syncthreads();

        // ---- k-loop: pure LDS-read + MFMA (W already in regs) ----
        f32x16 acc;
#pragma unroll
        for (int r = 0; r < 16; ++r) acc[r] = 0.f;
#pragma unroll
        for (int ks = 0; ks < 16; ++ks) {
            const f16x8 ah = Xh[(2 * ks + hiG) * 32 + lane31];
            const f16x8 al = Xl[(2 * ks + hiG) * 32 + lane31];
            const f16x8 wk = __builtin_bit_cast(f16x8, wfi[ks]);
            acc = __builtin_amdgcn_mfma_f32_32x32x16_f16(ah, wk, acc, 0, 0, 0);
            acc = __builtin_amdgcn_mfma_f32_32x32x16_f16(al, wk, acc, 0, 0, 0);
        }
        __syncthreads();   // X reads done; msg overlays Xl

        // ---- bias + raw messages -> msg[32][132] ----
#pragma unroll
        for (int r = 0; r < 16; ++r) {
            const int m = (r & 3) + 8 * (r >> 2) + 4 * hiG;
            msg[m * 132 + o] = acc[r] + bmv;
        }
        __syncthreads();

        // ---- LN stats, single pass (8 threads per row) ----
        {
            const int m = tid >> 3, c0 = tid & 7;
            float s = 0.f, s2 = 0.f;
#pragma unroll
            for (int i2 = 0; i2 < 16; ++i2) {
                const float v = msg[m * 132 + c0 + 8 * i2];
                s += v; s2 += v * v;
            }
            s  += __shfl_xor(s, 1, 64);  s  += __shfl_xor(s, 2, 64);  s  += __shfl_xor(s, 4, 64);
            s2 += __shfl_xor(s2, 1, 64); s2 += __shfl_xor(s2, 2, 64); s2 += __shfl_xor(s2, 4, 64);
            if (c0 == 0) {
                const float mu  = s * (1.f / 128.f);
                const float var = s2 * (1.f / 128.f) - mu * mu;
                s_mu[m] = mu;
                s_rs[m] = rsqrtf(var + EPS);
            }
        }
        __syncthreads();

        // ---- scatter: inline LN + run-merge over sorted receivers ----
        {
            int prev = -1; float accu = 0.f;
#pragma unroll
            for (int e = 0; e < 16; ++e) {
                const int ee = half * 16 + e;
                const int r  = s_recv[ee];
                const float val = (msg[ee * 132 + col] - s_mu[ee]) * s_rs[ee] * gv + bv;
                if (r != prev) {
                    if (prev >= 0) atomicAdd(abase + (size_t)prev * D, accu);
                    prev = r; accu = val;
                } else {
                    accu += val;
                }
            }
            if (prev >= 0) atomicAdd(abase + (size_t)prev * D, accu);
        }
        __syncthreads();   // protect X/msg before next tile's stage
    }
}

// ---------------- MFMA node kernel v4 (persistent, same template) --------
__global__ __launch_bounds__(256, 4)
void node_mfma(const float* __restrict__ nodes,
               const float* __restrict__ inbox,
               const unsigned char* __restrict__ wimg,
               const float* __restrict__ bn,
               const float* __restrict__ g2,
               const float* __restrict__ b2,
               float* __restrict__ out) {
    __shared__ __align__(16) unsigned char s_lds[33280];
    __shared__ float s_mu[ETILE];
    __shared__ float s_rs[ETILE];

    const int tid    = threadIdx.x;
    const int b      = blockIdx.x & 7;
    const int grp    = blockIdx.x >> 3;
    const int w      = tid >> 6;
    const int l      = tid & 63;
    const int lane31 = l & 31;
    const int hiG    = l >> 5;
    const int o      = w * 32 + lane31;

    intx4 wfi[16];
    {
        const intx4* img = (const intx4*)wimg;
#pragma unroll
        for (int ks = 0; ks < 16; ++ks)
            wfi[ks] = img[(2 * ks + hiG) * 128 + o];
#pragma unroll
        for (int ks = 0; ks < 16; ++ks)
            asm volatile("" : "+v"(wfi[ks]));
    }
    const float bnv = bn[o];
    const int   col  = tid & 127;
    const int   half = tid >> 7;
    const float gv = g2[col], bv = b2[col];

    const int i  = tid & 31;
    const int q8 = tid >> 5;
    f16x8* const Xh  = (f16x8*)s_lds;
    f16x8* const Xl  = (f16x8*)(s_lds + 16384);
    float* const msg = (float*)(s_lds + 16384);

    const int NTILES = (N_NODES + ETILE - 1) / ETILE;   // 313

    for (int it = 0; it < TPB_N; ++it) {
        const int tile = grp * TPB_N + it;
        if (tile >= NTILES) break;                       // uniform per block
        const int n0 = tile * ETILE;

        {
            int n = n0 + i;
            if (n >= N_NODES) n = N_NODES - 1;           // clamp loads
            const float* row = (q8 < 4)
                ? (nodes + ((size_t)b * N_NODES + n) * D + (q8 & 3) * 32)
                : (inbox + ((size_t)b * N_NODES + n) * D + (q8 & 3) * 32);
#pragma unroll
            for (int j = 0; j < 4; ++j) {
                const float4 va = *(const float4*)(row + 8 * j);
                const float4 vb = *(const float4*)(row + 8 * j + 4);
                const float xs[8] = {va.x, va.y, va.z, va.w, vb.x, vb.y, vb.z, vb.w};
                f16x8 h, lo;
#pragma unroll
                for (int u = 0; u < 8; ++u) {
                    h[u]  = (_Float16)xs[u];
                    lo[u] = (_Float16)(xs[u] - (float)h[u]);
                }
                const int g = 4 * q8 + j;
                Xh[g * 32 + i] = h;
                Xl[g * 32 + i] = lo;
            }
        }
        __syncthreads();

        f32x16 acc;
#pragma unroll
        for (int r = 0; r < 16; ++r) acc[r] = 0.f;
#pragma unroll
        for (int ks = 0; ks < 16; ++ks) {
            const f16x8 ah = Xh[(2 * ks + hiG) * 32 + lane31];
            const f16x8 al = Xl[(2 * ks + hiG) * 32 + lane31];
            const f16x8 wk = __builtin_bit_cast(f16x8, wfi[ks]);
            acc = __builtin_amdgcn_mfma_f32_32x32x16_f16(ah, wk, acc, 0, 0, 0);
            acc = __builtin_amdgcn_mfma_f32_32x32x16_f16(al, wk, acc, 0, 0, 0);
        }
        __syncthreads();

#pragma unroll
        for (int r = 0; r < 16; ++r) {
            const int m = (r & 3) + 8 * (r >> 2) + 4 * hiG;
            msg[m * 132 + o] = acc[r] + bnv;
        }
        __syncthreads();

        {
            const int m = tid >> 3, c0 = tid & 7;
            float s = 0.f, s2 = 0.f;
#pragma unroll
            for (int i2 = 0; i2 < 16; ++i2) {
                const float v = msg[m * 132 + c0 + 8 * i2];
                s += v; s2 += v * v;
            }
            s  += __shfl_xor(s, 1, 64);  s  += __shfl_xor(s, 2, 64);  s  += __shfl_xor(s, 4, 64);
            s2 += __shfl_xor(s2, 1, 64); s2 += __shfl_xor(s2, 2, 64); s2 += __shfl_xor(s2, 4, 64);
            if (c0 == 0) {
                const float mu  = s * (1.f / 128.f);
                const float var = s2 * (1.f / 128.f) - mu * mu;
                s_mu[m] = mu;
                s_rs[m] = rsqrtf(var + EPS);
            }
        }
        __syncthreads();

        {
#pragma unroll
            for (int e = 0; e < 16; ++e) {
                const int ee = half * 16 + e;
                const int n  = n0 + ee;
                if (n < N_NODES) {
                    out[((size_t)b * N_NODES + n) * D + col] =
                        (msg[ee * 132 + col] - s_mu[ee]) * s_rs[ee] * gv + bv;
                }
            }
        }
        __syncthreads();
    }
}

// ---------------- fp32 fallback kernels (proven R2, no workspace) ---------
__global__ __launch_bounds__(256, 2)
void edge_kernel(const float* __restrict__ nodes,
                 const float* __restrict__ Wm,
                 const float* __restrict__ bm,
                 const float* __restrict__ g1,
                 const float* __restrict__ b1,
                 const int*   __restrict__ senders,
                 const int*   __restrict__ receivers,
                 float* __restrict__ inbox) {
    __shared__ __align__(16) float ldsE[TWO_D][36];
    __shared__ __align__(16) float ldsW[64 * D];
    const int tid = threadIdx.x;
    const int b   = blockIdx.y;
    const int e0  = blockIdx.x * 32;
    const float* nb = nodes + (size_t)b * N_NODES * D;
    {
        const int i = tid >> 3, q0 = tid & 7, e = e0 + i;
        const float* rowR = nb + (size_t)receivers[e] * D;
        const float* rowS = nb + (size_t)senders[e] * D;
#pragma unroll
        for (int j = 0; j < 8; ++j) {
            const int k = (j * 8 + q0) * 4;
            const float4 v = (k < D) ? *(const float4*)(rowR + k)
                                     : *(const float4*)(rowS + (k - D));
            ldsE[k + 0][i] = v.x; ldsE[k + 1][i] = v.y;
            ldsE[k + 2][i] = v.z; ldsE[k + 3][i] = v.w;
        }
    }
    float acc[4][4];
#pragma unroll
    for (int a = 0; a < 4; ++a)
#pragma unroll
        for (int c = 0; c < 4; ++c) acc[a][c] = 0.0f;
    const int og = tid & 31, eg = tid >> 5;
    for (int kt = 0; kt < 4; ++kt) {
        __syncthreads();
        {
            const int oo = tid >> 1, half = tid & 1;
            const float* wrow = Wm + oo * TWO_D + kt * 64 + half * 32;
#pragma unroll
            for (int j = 0; j < 8; ++j) {
                const float4 w4 = *(const float4*)(wrow + j * 4);
                const int k2 = half * 32 + j * 4;
                ldsW[(k2 + 0) * D + oo] = w4.x; ldsW[(k2 + 1) * D + oo] = w4.y;
                ldsW[(k2 + 2) * D + oo] = w4.z; ldsW[(k2 + 3) * D + oo] = w4.w;
            }
        }
        __syncthreads();
#pragma unroll 4
        for (int k2 = 0; k2 < 64; ++k2) {
            const float4 wv = *(const float4*)&ldsW[k2 * D + 4 * og];
            const float4 xv = *(const float4*)&ldsE[kt * 64 + k2][4 * eg];
            const float wa[4] = {wv.x, wv.y, wv.z, wv.w};
            const float xa[4] = {xv.x, xv.y, xv.z, xv.w};
#pragma unroll
            for (int a = 0; a < 4; ++a)
#pragma unroll
                for (int c = 0; c < 4; ++c)
                    acc[a][c] = fmaf(xa[a], wa[c], acc[a][c]);
        }
    }
    const float4 bmv = *(const float4*)&bm[4 * og];
    const float4 g1v = *(const float4*)&g1[4 * og];
    const float4 b1v = *(const float4*)&b1[4 * og];
#pragma unroll
    for (int a = 0; a < 4; ++a) {
        acc[a][0] += bmv.x; acc[a][1] += bmv.y;
        acc[a][2] += bmv.z; acc[a][3] += bmv.w;
    }
    float mu[4], rs[4];
#pragma unroll
    for (int a = 0; a < 4; ++a) {
        float s = acc[a][0] + acc[a][1] + acc[a][2] + acc[a][3];
#pragma unroll
        for (int m = 16; m >= 1; m >>= 1) s += __shfl_xor(s, m, 64);
        mu[a] = s * (1.0f / 128.0f);
        const float d0 = acc[a][0] - mu[a], d1 = acc[a][1] - mu[a];
        const float d2 = acc[a][2] - mu[a], d3 = acc[a][3] - mu[a];
        float q = d0 * d0 + d1 * d1 + d2 * d2 + d3 * d3;
#pragma unroll
        for (int m = 16; m >= 1; m >>= 1) q += __shfl_xor(q, m, 64);
        rs[a] = rsqrtf(q * (1.0f / 128.0f) + EPS);
    }
#pragma unroll
    for (int a = 0; a < 4; ++a) {
        const int e = e0 + 4 * eg + a;
        const int r = receivers[e];
        float* dst = inbox + ((size_t)b * N_NODES + r) * D + 4 * og;
        atomicAdd(dst + 0, (acc[a][0] - mu[a]) * rs[a] * g1v.x + b1v.x);
        atomicAdd(dst + 1, (acc[a][1] - mu[a]) * rs[a] * g1v.y + b1v.y);
        atomicAdd(dst + 2, (acc[a][2] - mu[a]) * rs[a] * g1v.z + b1v.z);
        atomicAdd(dst + 3, (acc[a][3] - mu[a]) * rs[a] * g1v.w + b1v.w);
    }
}

__global__ __launch_bounds__(256, 2)
void node_kernel(const float* __restrict__ nodes,
                 const float* __restrict__ inbox,
                 const float* __restrict__ Wn,
                 const float* __restrict__ bn,
                 const float* __restrict__ g2,
                 const float* __restrict__ b2,
                 float* __restrict__ out) {
    __shared__ __align__(16) float ldsE[TWO_D][36];
    __shared__ __align__(16) float ldsW[64 * D];
    const int tid = threadIdx.x;
    const int b   = blockIdx.y;
    const int n0  = blockIdx.x * 32;
    {
        const int i = tid >> 3, q0 = tid & 7;
        int n = n0 + i;
        if (n >= N_NODES) n = N_NODES - 1;
        const float* rowN = nodes + ((size_t)b * N_NODES + n) * D;
        const float* rowI = inbox + ((size_t)b * N_NODES + n) * D;
#pragma unroll
        for (int j = 0; j < 8; ++j) {
            const int k = (j * 8 + q0) * 4;
            const float4 v = (k < D) ? *(const float4*)(rowN + k)
                                     : *(const float4*)(rowI + (k - D));
            ldsE[k + 0][i] = v.x; ldsE[k + 1][i] = v.y;
            ldsE[k + 2][i] = v.z; ldsE[k + 3][i] = v.w;
        }
    }
    float acc[4][4];
#pragma unroll
    for (int a = 0; a < 4; ++a)
#pragma unroll
        for (int c = 0; c < 4; ++c) acc[a][c] = 0.0f;
    const int og = tid & 31, eg = tid >> 5;
    for (int kt = 0; kt < 4; ++kt) {
        __syncthreads();
        {
            const int oo = tid >> 1, half = tid & 1;
            const float* wrow = Wn + oo * TWO_D + kt * 64 + half * 32;
#pragma unroll
            for (int j = 0; j < 8; ++j) {
                const float4 w4 = *(const float4*)(wrow + j * 4);
                const int k2 = half * 32 + j * 4;
                ldsW[(k2 + 0) * D + oo] = w4.x; ldsW[(k2 + 1) * D + oo] = w4.y;
                ldsW[(k2 + 2) * D + oo] = w4.z; ldsW[(k2 + 3) * D + oo] = w4.w;
            }
        }
        __syncthreads();
#pragma unroll 4
        for (int k2 = 0; k2 < 64; ++k2) {
            const float4 wv = *(const float4*)&ldsW[k2 * D + 4 * og];
            const float4 xv = *(const float4*)&ldsE[kt * 64 + k2][4 * eg];
            const float wa[4] = {wv.x, wv.y, wv.z, wv.w};
            const float xa[4] = {xv.x, xv.y, xv.z, xv.w};
#pragma unroll
            for (int a = 0; a < 4; ++a)
#pragma unroll
                for (int c = 0; c < 4; ++c)
                    acc[a][c] = fmaf(xa[a], wa[c], acc[a][c]);
        }
    }
    const float4 bnv = *(const float4*)&bn[4 * og];
    const float4 g2v = *(const float4*)&g2[4 * og];
    const float4 b2v = *(const float4*)&b2[4 * og];
#pragma unroll
    for (int a = 0; a < 4; ++a) {
        acc[a][0] += bnv.x; acc[a][1] += bnv.y;
        acc[a][2] += bnv.z; acc[a][3] += bnv.w;
    }
    float mu[4], rs[4];
#pragma unroll
    for (int a = 0; a < 4; ++a) {
        float s = acc[a][0] + acc[a][1] + acc[a][2] + acc[a][3];
#pragma unroll
        for (int m = 16; m >= 1; m >>= 1) s += __shfl_xor(s, m, 64);
        mu[a] = s * (1.0f / 128.0f);
        const float d0 = acc[a][0] - mu[a], d1 = acc[a][1] - mu[a];
        const float d2 = acc[a][2] - mu[a], d3 = acc[a][3] - mu[a];
        float q = d0 * d0 + d1 * d1 + d2 * d2 + d3 * d3;
#pragma unroll
        for (int m = 16; m >= 1; m >>= 1) q += __shfl_xor(q, m, 64);
        rs[a] = rsqrtf(q * (1.0f / 128.0f) + EPS);
    }
#pragma unroll
    for (int a = 0; a < 4; ++a) {
        const int n = n0 + 4 * eg + a;
        if (n < N_NODES) {
            float4 o4;
            o4.x = (acc[a][0] - mu[a]) * rs[a] * g2v.x + b2v.x;
            o4.y = (acc[a][1] - mu[a]) * rs[a] * g2v.y + b2v.y;
            o4.z = (acc[a][2] - mu[a]) * rs[a] * g2v.z + b2v.z;
            o4.w = (acc[a][3] - mu[a]) * rs[a] * g2v.w + b2v.w;
            *(float4*)(out + ((size_t)b * N_NODES + n) * D + 4 * og) = o4;
        }
    }
}

// ---------------------------------------------------------------------------
extern "C" void kernel_launch(void* const* d_in, const int* in_sizes, int n_in,
                              void* d_out, int out_size, void* d_ws, size_t ws_size,
                              hipStream_t stream) {
    const float* nodes     = (const float*)d_in[0];
    const float* Wm        = (const float*)d_in[1];
    const float* bm        = (const float*)d_in[2];
    const float* g1        = (const float*)d_in[3];
    const float* b1        = (const float*)d_in[4];
    const float* Wn        = (const float*)d_in[5];
    const float* bn        = (const float*)d_in[6];
    const float* g2        = (const float*)d_in[7];
    const float* b2        = (const float*)d_in[8];
    const int*   senders   = (const int*)d_in[9];
    const int*   receivers = (const int*)d_in[10];
    float*       out       = (float*)d_out;

    const long long inbox_n = (long long)BATCH * N_NODES * D;   // 10.24M floats
    // ws: [0,64K) img_m | [64K,128K) img_n | [128K,+720K) sort | [1M,+41MB) inbox
    const size_t SCRATCH_NEED = 131072 + 720128;

    if (d_ws != nullptr && ws_size >= SCRATCH_NEED) {
        unsigned char* wsb  = (unsigned char*)d_ws;
        unsigned char* wimg = wsb;                 // img_m @0, img_n @65536
        int* ints   = (int*)(wsb + 131072);
        int* counts = ints;            // 10000 (16B aligned)
        int* cursor = ints + 10016;    // 10000
        int* perm   = ints + 20032;    // 160000
        float* inbox = (ws_size >= (size_t)1048576 + (size_t)inbox_n * 4)
                           ? (float*)(wsb + 1048576) : out;

        zero_kernel<<<dim3(10),   dim3(256), 0, stream>>>((float4*)counts, 2500);
        zero_kernel<<<dim3(2048), dim3(256), 0, stream>>>((float4*)inbox, inbox_n / 4);
        prep_w<<<dim3(16), dim3(256), 0, stream>>>(Wm, Wn, wimg);
        hist_kernel<<<dim3(625), dim3(256), 0, stream>>>(receivers, counts);
        scan_kernel<<<dim3(1), dim3(1024), 0, stream>>>(counts, cursor);
        scatter_kernel<<<dim3(625), dim3(256), 0, stream>>>(receivers, cursor, perm);

        // 1-D grid, batch = bid & 7 -> XCD-pinned batches (5000 blocks)
        edge_mfma<<<dim3(N_EDGES / ETILE / TPB_E * BATCH), dim3(256), 0, stream>>>(
            nodes, wimg, bm, g1, b1, senders, receivers, perm, inbox);

        // 313 node tiles -> 40 groups x 8 batches = 320 blocks
        const int ntiles = (N_NODES + ETILE - 1) / ETILE;
        node_mfma<<<dim3((ntiles + TPB_N - 1) / TPB_N * BATCH), dim3(256), 0, stream>>>(
            nodes, inbox, wimg + 65536, bn, g2, b2, out);
    } else {
        // proven fp32 fallback (no workspace needed)
        float* inbox = out;
        zero_kernel<<<dim3(2048), dim3(256), 0, stream>>>((float4*)inbox, inbox_n / 4);
        edge_kernel<<<dim3(N_EDGES / 32, BATCH), dim3(256), 0, stream>>>(
            nodes, Wm, bm, g1, b1, senders, receivers, inbox);
        node_kernel<<<dim3((N_NODES + 31) / 32, BATCH), dim3(256), 0, stream>>>(
            nodes, inbox, Wn, bn, g2, b2, out);
    }
}